// Round 10
// baseline (234.426 us; speedup 1.0000x reference)
//
#include <hip/hip_runtime.h>

#define NFEAT 512
#define HID 16
#define MAXNB 512          // max buckets (N/256 = 391 for N=100K)
#define NBLK 256           // blocks for hist/scatter passes (chunking must match)
#define PACK_SHIFT 17      // src fits in 17 bits (N < 131072)
#define PACK_MASK ((1 << PACK_SHIFT) - 1)

// ============ pass A: per-(block,bucket) histogram ============
__global__ __launch_bounds__(512) void k_hist2d(const int* __restrict__ ei,
                                                int* __restrict__ cnt_t,
                                                int E, int nb) {
  __shared__ int l[MAXNB];
  for (int i = threadIdx.x; i < nb; i += 512) l[i] = 0;
  __syncthreads();
  int chunk = (E + NBLK - 1) / NBLK;
  int beg = blockIdx.x * chunk;
  int end = beg + chunk; if (end > E) end = E;
  for (int e = beg + threadIdx.x; e < end; e += 512)
    atomicAdd(&l[ei[(size_t)E + e] >> 8], 1);
  __syncthreads();
  for (int b = threadIdx.x; b < nb; b += 512)
    cnt_t[(size_t)b * NBLK + blockIdx.x] = l[b];
}

// ============ per-bucket column scan (one wave per bucket) ============
__global__ __launch_bounds__(64) void k_colscan(const int* __restrict__ cnt_t,
                                                int* __restrict__ off_t,
                                                int* __restrict__ gcnt, int nb) {
  int b = blockIdx.x;
  if (b >= nb) return;
  int lane = threadIdx.x;
  int4 v = *(const int4*)&cnt_t[(size_t)b * NBLK + lane * 4];
  int tot = v.x + v.y + v.z + v.w;
  int s = tot;
  for (int d = 1; d < 64; d <<= 1) {
    int o = __shfl_up(s, d);
    if (lane >= d) s += o;
  }
  int excl = s - tot;
  int4 w;
  w.x = excl;
  w.y = excl + v.x;
  w.z = excl + v.x + v.y;
  w.w = excl + v.x + v.y + v.z;
  *(int4*)&off_t[(size_t)b * NBLK + lane * 4] = w;
  if (lane == 63) gcnt[b] = s;
}

// ============ scan: 16-aligned bucket bases ============
__global__ __launch_bounds__(512) void k_bscan(const int* __restrict__ gcnt,
                                               int* __restrict__ gbase, int nb) {
  __shared__ int sm[512];
  int t = threadIdx.x;
  int c = (t < nb) ? gcnt[t] : 0;
  int pc = (c + 15) & ~15;
  sm[t] = pc;
  __syncthreads();
  for (int off = 1; off < 512; off <<= 1) {
    int x = (t >= off) ? sm[t - off] : 0;
    __syncthreads();
    sm[t] += x;
    __syncthreads();
  }
  if (t < nb) gbase[t] = sm[t] - pc;
}

// ============ pass B: scatter with precomputed deterministic offsets ============
__global__ __launch_bounds__(512) void k_scatter2(const int* __restrict__ ei,
                                                  const int* __restrict__ gbase,
                                                  const int* __restrict__ off_t,
                                                  int* __restrict__ binned,
                                                  int E, int nb) {
  __shared__ int cur[MAXNB];
  for (int b = threadIdx.x; b < nb; b += 512)
    cur[b] = gbase[b] + off_t[(size_t)b * NBLK + blockIdx.x];
  __syncthreads();
  int chunk = (E + NBLK - 1) / NBLK;
  int beg = blockIdx.x * chunk;
  int end = beg + chunk; if (end > E) end = E;
  for (int e = beg + threadIdx.x; e < end; e += 512) {
    int s = ei[e];
    int d = ei[(size_t)E + e];
    int b = d >> 8;
    int pos = atomicAdd(&cur[b], 1);
    binned[pos] = s | ((d & 255) << PACK_SHIFT);
  }
}

// ============ per-bucket sort -> per-node CSR + dinv ============
__global__ __launch_bounds__(256) void k_sortbucket(const int* __restrict__ gbase,
                                                    const int* __restrict__ gcnt,
                                                    const int* __restrict__ binned,
                                                    int* __restrict__ csr,
                                                    int* __restrict__ rowbeg,
                                                    int* __restrict__ rowend,
                                                    float* __restrict__ dinv, int N) {
  __shared__ int hist[256];
  __shared__ int sm[256];
  __shared__ int cur[256];
  const int t = threadIdx.x;
  const int b = blockIdx.x;
  const int base = gbase[b], cnt = gcnt[b];
  hist[t] = 0;
  __syncthreads();
  for (int j = base + t; j < base + cnt; j += 256)
    atomicAdd(&hist[binned[j] >> PACK_SHIFT], 1);
  __syncthreads();
  int h = hist[t];
  sm[t] = h;
  __syncthreads();
  for (int off = 1; off < 256; off <<= 1) {
    int x = (t >= off) ? sm[t - off] : 0;
    __syncthreads();
    sm[t] += x;
    __syncthreads();
  }
  int incl = sm[t];
  int excl = incl - h;
  cur[t] = excl;
  int node = b * 256 + t;
  if (node < N) {
    rowbeg[node] = base + excl;
    rowend[node] = base + incl;
    dinv[node] = rsqrtf((float)h + 1.0f);
  }
  __syncthreads();
  for (int j = base + t; j < base + cnt; j += 256) {
    int val = binned[j];
    int pos = atomicAdd(&cur[val >> PACK_SHIFT], 1);
    csr[base + pos] = val & PACK_MASK;
  }
}

// ============ GEMM1: h1s = (x @ W1) * dinv[row] — scalar-W streaming ============
// Thread = one full row (K=512). W addresses depend only on loop induction ->
// wave-uniform -> compiler emits s_load (scalar cache, no LDS/VMEM pressure).
// FMA: v_fmac acc(VGPR) += sW(SGPR) * x(VGPR). No LDS, no barriers.
__device__ __forceinline__ void fma4(float4& a, float s, const float4& b) {
  a.x += s * b.x;
  a.y += s * b.y;
  a.z += s * b.z;
  a.w += s * b.w;
}

__device__ __forceinline__ void dostepW(float s, const float4* __restrict__ W4, int k,
                                        float4& a0, float4& a1, float4& a2, float4& a3) {
  fma4(a0, s, W4[k * 4 + 0]);
  fma4(a1, s, W4[k * 4 + 1]);
  fma4(a2, s, W4[k * 4 + 2]);
  fma4(a3, s, W4[k * 4 + 3]);
}

__device__ __forceinline__ void kstep16(float4 c0, float4 c1, float4 c2, float4 c3,
                                        const float4* __restrict__ W4, int kbase,
                                        float4& a0, float4& a1, float4& a2, float4& a3) {
  dostepW(c0.x, W4, kbase + 0, a0, a1, a2, a3);
  dostepW(c0.y, W4, kbase + 1, a0, a1, a2, a3);
  dostepW(c0.z, W4, kbase + 2, a0, a1, a2, a3);
  dostepW(c0.w, W4, kbase + 3, a0, a1, a2, a3);
  dostepW(c1.x, W4, kbase + 4, a0, a1, a2, a3);
  dostepW(c1.y, W4, kbase + 5, a0, a1, a2, a3);
  dostepW(c1.z, W4, kbase + 6, a0, a1, a2, a3);
  dostepW(c1.w, W4, kbase + 7, a0, a1, a2, a3);
  dostepW(c2.x, W4, kbase + 8, a0, a1, a2, a3);
  dostepW(c2.y, W4, kbase + 9, a0, a1, a2, a3);
  dostepW(c2.z, W4, kbase + 10, a0, a1, a2, a3);
  dostepW(c2.w, W4, kbase + 11, a0, a1, a2, a3);
  dostepW(c3.x, W4, kbase + 12, a0, a1, a2, a3);
  dostepW(c3.y, W4, kbase + 13, a0, a1, a2, a3);
  dostepW(c3.z, W4, kbase + 14, a0, a1, a2, a3);
  dostepW(c3.w, W4, kbase + 15, a0, a1, a2, a3);
}

__global__ __launch_bounds__(256) void k_gemm1(const float* __restrict__ x,
                                               const float* __restrict__ W,
                                               const float* __restrict__ dinv,
                                               float* __restrict__ h1s, int N) {
  int row = blockIdx.x * 256 + threadIdx.x;
  const bool valid = row < N;
  if (row > N - 1) row = N - 1;
  const float4* xr = (const float4*)(x + (size_t)row * NFEAT);
  const float4* W4 = (const float4*)W;

  float4 a0 = make_float4(0.f, 0.f, 0.f, 0.f), a1 = a0, a2 = a0, a3 = a0;

  // ping-pong 64B chunks (4 float4 = 16 k each), 32 chunks total
  float4 A0 = xr[0], A1 = xr[1], A2 = xr[2], A3 = xr[3];
  float4 B0, B1, B2, B3;
#pragma unroll 1
  for (int c = 0; c < 32; c += 2) {
    B0 = xr[(c + 1) * 4 + 0];
    B1 = xr[(c + 1) * 4 + 1];
    B2 = xr[(c + 1) * 4 + 2];
    B3 = xr[(c + 1) * 4 + 3];
    kstep16(A0, A1, A2, A3, W4, c * 16, a0, a1, a2, a3);
    if (c + 2 < 32) {
      A0 = xr[(c + 2) * 4 + 0];
      A1 = xr[(c + 2) * 4 + 1];
      A2 = xr[(c + 2) * 4 + 2];
      A3 = xr[(c + 2) * 4 + 3];
    }
    kstep16(B0, B1, B2, B3, W4, (c + 1) * 16, a0, a1, a2, a3);
  }

  if (valid) {
    float di = dinv[row];
    a0.x *= di; a0.y *= di; a0.z *= di; a0.w *= di;
    a1.x *= di; a1.y *= di; a1.z *= di; a1.w *= di;
    a2.x *= di; a2.y *= di; a2.z *= di; a2.w *= di;
    a3.x *= di; a3.y *= di; a3.z *= di; a3.w *= di;
    float4* o = (float4*)(h1s + (size_t)row * HID);
    o[0] = a0; o[1] = a1; o[2] = a2; o[3] = a3;
  }
}

// ===== layer1 aggregation + relu + W2, fused. 16 lanes per node. =====
__global__ __launch_bounds__(256) void k_agg1f(const int* __restrict__ rowbeg,
                                               const int* __restrict__ rowend,
                                               const int* __restrict__ csr,
                                               const float* __restrict__ h1s,
                                               const float* __restrict__ dinv,
                                               const float* __restrict__ b1,
                                               const float* __restrict__ W2,
                                               float* __restrict__ h2s, int N) {
  const int f = threadIdx.x & 15;
  const int node = blockIdx.x * 16 + (threadIdx.x >> 4);
  if (node >= N) return;
  int j = rowbeg[node];
  const int end = rowend[node];
  float acc = h1s[(size_t)node * HID + f];  // self loop (pre-scaled)
  for (; j < end && (j & 3); ++j) acc += h1s[(size_t)csr[j] * HID + f];
  for (; j + 4 <= end; j += 4) {
    int4 ss = *(const int4*)&csr[j];  // broadcast within group
    float a0 = h1s[(size_t)ss.x * HID + f];
    float a1 = h1s[(size_t)ss.y * HID + f];
    float a2 = h1s[(size_t)ss.z * HID + f];
    float a3 = h1s[(size_t)ss.w * HID + f];
    acc += (a0 + a1) + (a2 + a3);
  }
  for (; j < end; ++j) acc += h1s[(size_t)csr[j] * HID + f];

  float di = dinv[node];
  float v = fmaxf(acc * di + b1[f], 0.f);
  float o0 = v * W2[f * 2 + 0];
  float o1 = v * W2[f * 2 + 1];
#pragma unroll
  for (int d = 1; d < 16; d <<= 1) {
    o0 += __shfl_xor(o0, d);
    o1 += __shfl_xor(o1, d);
  }
  if (f == 0) *(float2*)&h2s[(size_t)node * 2] = make_float2(o0 * di, o1 * di);
}

// ===== layer2 aggregation + bias, fused. thread per node. =====
__global__ __launch_bounds__(256) void k_agg2f(const int* __restrict__ rowbeg,
                                               const int* __restrict__ rowend,
                                               const int* __restrict__ csr,
                                               const float* __restrict__ h2s,
                                               const float* __restrict__ dinv,
                                               const float* __restrict__ b2,
                                               float* __restrict__ out, int N) {
  int i = blockIdx.x * 256 + threadIdx.x;
  if (i >= N) return;
  int j = rowbeg[i];
  const int end = rowend[i];
  float2 o = *(const float2*)&h2s[(size_t)i * 2];  // self loop
  for (; j < end && (j & 3); ++j) {
    float2 v = *(const float2*)&h2s[(size_t)csr[j] * 2];
    o.x += v.x; o.y += v.y;
  }
  for (; j + 4 <= end; j += 4) {
    int4 ss = *(const int4*)&csr[j];
    float2 v0 = *(const float2*)&h2s[(size_t)ss.x * 2];
    float2 v1 = *(const float2*)&h2s[(size_t)ss.y * 2];
    float2 v2 = *(const float2*)&h2s[(size_t)ss.z * 2];
    float2 v3 = *(const float2*)&h2s[(size_t)ss.w * 2];
    o.x += (v0.x + v1.x) + (v2.x + v3.x);
    o.y += (v0.y + v1.y) + (v2.y + v3.y);
  }
  for (; j < end; ++j) {
    float2 v = *(const float2*)&h2s[(size_t)csr[j] * 2];
    o.x += v.x; o.y += v.y;
  }
  float di = dinv[i];
  o.x = o.x * di + b2[0];
  o.y = o.y * di + b2[1];
  *(float2*)&out[(size_t)i * 2] = o;
}

// ================= launch =================
extern "C" void kernel_launch(void* const* d_in, const int* in_sizes, int n_in,
                              void* d_out, int out_size, void* d_ws, size_t ws_size,
                              hipStream_t stream) {
  const float* x = (const float*)d_in[0];
  const int* ei = (const int*)d_in[1];  // harness delivers integer inputs as int32
  const float* W1 = (const float*)d_in[2];
  const float* b1 = (const float*)d_in[3];
  const float* W2 = (const float*)d_in[4];
  const float* b2 = (const float*)d_in[5];
  float* out = (float*)d_out;
  const int N = in_sizes[0] / NFEAT;
  const int E = in_sizes[1] / 2;
  const int nb = (N + 255) / 256;  // buckets of 256 nodes

  char* p = (char*)d_ws;
  int* cnt_t = (int*)p;    p += (size_t)MAXNB * NBLK * 4;
  int* off_t = (int*)p;    p += (size_t)MAXNB * NBLK * 4;
  int* gcnt = (int*)p;     p += (size_t)MAXNB * 4;
  int* gbase = (int*)p;    p += (size_t)MAXNB * 4;
  int* binned = (int*)p;   p += ((size_t)E + MAXNB * 16) * 4;
  int* csr = (int*)p;      p += ((size_t)E + MAXNB * 16) * 4;
  int* rowbeg = (int*)p;   p += (size_t)N * 4;
  int* rowend = (int*)p;   p += (size_t)N * 4;
  float* dinv = (float*)p; p += (size_t)N * 4;
  float* h1s = (float*)p;  p += (size_t)N * HID * 4;
  float* h2s = (float*)p;  p += (size_t)N * 2 * 4;

  k_hist2d<<<NBLK, 512, 0, stream>>>(ei, cnt_t, E, nb);
  k_colscan<<<nb, 64, 0, stream>>>(cnt_t, off_t, gcnt, nb);
  k_bscan<<<1, 512, 0, stream>>>(gcnt, gbase, nb);
  k_scatter2<<<NBLK, 512, 0, stream>>>(ei, gbase, off_t, binned, E, nb);
  k_sortbucket<<<nb, 256, 0, stream>>>(gbase, gcnt, binned, csr, rowbeg, rowend, dinv, N);
  k_gemm1<<<(N + 255) / 256, 256, 0, stream>>>(x, W1, dinv, h1s, N);
  k_agg1f<<<(N + 15) / 16, 256, 0, stream>>>(rowbeg, rowend, csr, h1s, dinv, b1, W2, h2s, N);
  k_agg2f<<<(N + 255) / 256, 256, 0, stream>>>(rowbeg, rowend, csr, h2s, dinv, b2, out, N);
}

// Round 11
// 203.670 us; speedup vs baseline: 1.1510x; 1.1510x over previous
//
#include <hip/hip_runtime.h>

#define NFEAT 512
#define HID 16
#define MAXNB 512          // max buckets (N/256 = 391 for N=100K)
#define NBLK 256           // blocks for hist/scatter passes (chunking must match)
#define PACK_SHIFT 17      // src fits in 17 bits (N < 131072)
#define PACK_MASK ((1 << PACK_SHIFT) - 1)

// ============ pass A: per-(block,bucket) histogram ============
__global__ __launch_bounds__(512) void k_hist2d(const int* __restrict__ ei,
                                                int* __restrict__ cnt_t,
                                                int E, int nb) {
  __shared__ int l[MAXNB];
  for (int i = threadIdx.x; i < nb; i += 512) l[i] = 0;
  __syncthreads();
  int chunk = (E + NBLK - 1) / NBLK;
  int beg = blockIdx.x * chunk;
  int end = beg + chunk; if (end > E) end = E;
  for (int e = beg + threadIdx.x; e < end; e += 512)
    atomicAdd(&l[ei[(size_t)E + e] >> 8], 1);
  __syncthreads();
  for (int b = threadIdx.x; b < nb; b += 512)
    cnt_t[(size_t)b * NBLK + blockIdx.x] = l[b];
}

// ============ per-bucket column scan (one wave per bucket) ============
__global__ __launch_bounds__(64) void k_colscan(const int* __restrict__ cnt_t,
                                                int* __restrict__ off_t,
                                                int* __restrict__ gcnt, int nb) {
  int b = blockIdx.x;
  if (b >= nb) return;
  int lane = threadIdx.x;
  int4 v = *(const int4*)&cnt_t[(size_t)b * NBLK + lane * 4];
  int tot = v.x + v.y + v.z + v.w;
  int s = tot;
  for (int d = 1; d < 64; d <<= 1) {
    int o = __shfl_up(s, d);
    if (lane >= d) s += o;
  }
  int excl = s - tot;
  int4 w;
  w.x = excl;
  w.y = excl + v.x;
  w.z = excl + v.x + v.y;
  w.w = excl + v.x + v.y + v.z;
  *(int4*)&off_t[(size_t)b * NBLK + lane * 4] = w;
  if (lane == 63) gcnt[b] = s;
}

// ============ scan: 16-aligned bucket bases ============
__global__ __launch_bounds__(512) void k_bscan(const int* __restrict__ gcnt,
                                               int* __restrict__ gbase, int nb) {
  __shared__ int sm[512];
  int t = threadIdx.x;
  int c = (t < nb) ? gcnt[t] : 0;
  int pc = (c + 15) & ~15;
  sm[t] = pc;
  __syncthreads();
  for (int off = 1; off < 512; off <<= 1) {
    int x = (t >= off) ? sm[t - off] : 0;
    __syncthreads();
    sm[t] += x;
    __syncthreads();
  }
  if (t < nb) gbase[t] = sm[t] - pc;
}

// ============ pass B: scatter with precomputed deterministic offsets ============
__global__ __launch_bounds__(512) void k_scatter2(const int* __restrict__ ei,
                                                  const int* __restrict__ gbase,
                                                  const int* __restrict__ off_t,
                                                  int* __restrict__ binned,
                                                  int E, int nb) {
  __shared__ int cur[MAXNB];
  for (int b = threadIdx.x; b < nb; b += 512)
    cur[b] = gbase[b] + off_t[(size_t)b * NBLK + blockIdx.x];
  __syncthreads();
  int chunk = (E + NBLK - 1) / NBLK;
  int beg = blockIdx.x * chunk;
  int end = beg + chunk; if (end > E) end = E;
  for (int e = beg + threadIdx.x; e < end; e += 512) {
    int s = ei[e];
    int d = ei[(size_t)E + e];
    int b = d >> 8;
    int pos = atomicAdd(&cur[b], 1);
    binned[pos] = s | ((d & 255) << PACK_SHIFT);
  }
}

// ============ per-bucket sort -> per-node CSR + dinv ============
__global__ __launch_bounds__(256) void k_sortbucket(const int* __restrict__ gbase,
                                                    const int* __restrict__ gcnt,
                                                    const int* __restrict__ binned,
                                                    int* __restrict__ csr,
                                                    int* __restrict__ rowbeg,
                                                    int* __restrict__ rowend,
                                                    float* __restrict__ dinv, int N) {
  __shared__ int hist[256];
  __shared__ int sm[256];
  __shared__ int cur[256];
  const int t = threadIdx.x;
  const int b = blockIdx.x;
  const int base = gbase[b], cnt = gcnt[b];
  hist[t] = 0;
  __syncthreads();
  for (int j = base + t; j < base + cnt; j += 256)
    atomicAdd(&hist[binned[j] >> PACK_SHIFT], 1);
  __syncthreads();
  int h = hist[t];
  sm[t] = h;
  __syncthreads();
  for (int off = 1; off < 256; off <<= 1) {
    int x = (t >= off) ? sm[t - off] : 0;
    __syncthreads();
    sm[t] += x;
    __syncthreads();
  }
  int incl = sm[t];
  int excl = incl - h;
  cur[t] = excl;
  int node = b * 256 + t;
  if (node < N) {
    rowbeg[node] = base + excl;
    rowend[node] = base + incl;
    dinv[node] = rsqrtf((float)h + 1.0f);
  }
  __syncthreads();
  for (int j = base + t; j < base + cnt; j += 256) {
    int val = binned[j];
    int pos = atomicAdd(&cur[val >> PACK_SHIFT], 1);
    csr[base + pos] = val & PACK_MASK;
  }
}

// ============ GEMM1: h1s = (x @ W1) * dinv[row] — streaming, M=2 rows/thread ====
// 128 rows/block (782 blocks), 256 thr = 4 waves; wave w = K-quarter.
// Lane handles rows (lane, lane+64): each W ds_read feeds 8 FMAs (2 rows x 4).
// No barriers in the K loop; one final LDS partial-sum reduce.
#define GR2 128

__device__ __forceinline__ void fma4(float4& a, float s, const float4& b) {
  a.x += s * b.x;
  a.y += s * b.y;
  a.z += s * b.z;
  a.w += s * b.w;
}

__device__ __forceinline__ void kstep2(float s0, float s1, const float4* __restrict__ sW4,
                                       int k,
                                       float4& a00, float4& a01, float4& a02, float4& a03,
                                       float4& a10, float4& a11, float4& a12, float4& a13) {
  float4 w0 = sW4[k * 4 + 0];
  float4 w1 = sW4[k * 4 + 1];
  float4 w2 = sW4[k * 4 + 2];
  float4 w3 = sW4[k * 4 + 3];
  fma4(a00, s0, w0); fma4(a01, s0, w1); fma4(a02, s0, w2); fma4(a03, s0, w3);
  fma4(a10, s1, w0); fma4(a11, s1, w1); fma4(a12, s1, w2); fma4(a13, s1, w3);
}

__global__ __launch_bounds__(256) void k_gemm1(const float* __restrict__ x,
                                               const float* __restrict__ W,
                                               const float* __restrict__ dinv,
                                               float* __restrict__ h1s, int N) {
  __shared__ float sW[NFEAT * HID];         // 32 KB
  __shared__ float part[4][GR2][HID + 4];   // 40 KB, 80B row stride (16B aligned)
  float4* sW4 = (float4*)sW;
  const float4* W4 = (const float4*)W;
  for (int i = threadIdx.x; i < NFEAT * HID / 4; i += 256) sW4[i] = W4[i];
  __syncthreads();

  const int w = threadIdx.x >> 6;     // K-quarter
  const int lane = threadIdx.x & 63;
  const int Nm1 = N - 1;
  int r0 = blockIdx.x * GR2 + lane;      if (r0 > Nm1) r0 = Nm1;
  int r1 = blockIdx.x * GR2 + 64 + lane; if (r1 > Nm1) r1 = Nm1;
  const float4* x0 = (const float4*)(x + (size_t)r0 * NFEAT) + w * 32;
  const float4* x1 = (const float4*)(x + (size_t)r1 * NFEAT) + w * 32;

  float4 z = make_float4(0.f, 0.f, 0.f, 0.f);
  float4 a00 = z, a01 = z, a02 = z, a03 = z;
  float4 a10 = z, a11 = z, a12 = z, a13 = z;

  float4 A0 = x0[0], A1 = x0[1], A2 = x0[2], A3 = x0[3];
  float4 B0 = x1[0], B1 = x1[1], B2 = x1[2], B3 = x1[3];
  const int kbase = w * 128;
#pragma unroll
  for (int g = 0; g < 8; ++g) {
    float4 c0 = A0, c1 = A1, c2 = A2, c3 = A3;
    float4 d0 = B0, d1 = B1, d2 = B2, d3 = B3;
    if (g < 7) {
      A0 = x0[g * 4 + 4]; A1 = x0[g * 4 + 5]; A2 = x0[g * 4 + 6]; A3 = x0[g * 4 + 7];
      B0 = x1[g * 4 + 4]; B1 = x1[g * 4 + 5]; B2 = x1[g * 4 + 6]; B3 = x1[g * 4 + 7];
    }
    int k0 = kbase + g * 16;
    kstep2(c0.x, d0.x, sW4, k0 + 0,  a00, a01, a02, a03, a10, a11, a12, a13);
    kstep2(c0.y, d0.y, sW4, k0 + 1,  a00, a01, a02, a03, a10, a11, a12, a13);
    kstep2(c0.z, d0.z, sW4, k0 + 2,  a00, a01, a02, a03, a10, a11, a12, a13);
    kstep2(c0.w, d0.w, sW4, k0 + 3,  a00, a01, a02, a03, a10, a11, a12, a13);
    kstep2(c1.x, d1.x, sW4, k0 + 4,  a00, a01, a02, a03, a10, a11, a12, a13);
    kstep2(c1.y, d1.y, sW4, k0 + 5,  a00, a01, a02, a03, a10, a11, a12, a13);
    kstep2(c1.z, d1.z, sW4, k0 + 6,  a00, a01, a02, a03, a10, a11, a12, a13);
    kstep2(c1.w, d1.w, sW4, k0 + 7,  a00, a01, a02, a03, a10, a11, a12, a13);
    kstep2(c2.x, d2.x, sW4, k0 + 8,  a00, a01, a02, a03, a10, a11, a12, a13);
    kstep2(c2.y, d2.y, sW4, k0 + 9,  a00, a01, a02, a03, a10, a11, a12, a13);
    kstep2(c2.z, d2.z, sW4, k0 + 10, a00, a01, a02, a03, a10, a11, a12, a13);
    kstep2(c2.w, d2.w, sW4, k0 + 11, a00, a01, a02, a03, a10, a11, a12, a13);
    kstep2(c3.x, d3.x, sW4, k0 + 12, a00, a01, a02, a03, a10, a11, a12, a13);
    kstep2(c3.y, d3.y, sW4, k0 + 13, a00, a01, a02, a03, a10, a11, a12, a13);
    kstep2(c3.z, d3.z, sW4, k0 + 14, a00, a01, a02, a03, a10, a11, a12, a13);
    kstep2(c3.w, d3.w, sW4, k0 + 15, a00, a01, a02, a03, a10, a11, a12, a13);
  }

  *(float4*)&part[w][lane][0] = a00;
  *(float4*)&part[w][lane][4] = a01;
  *(float4*)&part[w][lane][8] = a02;
  *(float4*)&part[w][lane][12] = a03;
  *(float4*)&part[w][64 + lane][0] = a10;
  *(float4*)&part[w][64 + lane][4] = a11;
  *(float4*)&part[w][64 + lane][8] = a12;
  *(float4*)&part[w][64 + lane][12] = a13;
  __syncthreads();

#pragma unroll
  for (int i = 0; i < 2; ++i) {
    int t = threadIdx.x + (i << 8);
    int r = t >> 2, jq = t & 3;
    float4 s0 = *(const float4*)&part[0][r][jq * 4];
    float4 s1 = *(const float4*)&part[1][r][jq * 4];
    float4 s2 = *(const float4*)&part[2][r][jq * 4];
    float4 s3 = *(const float4*)&part[3][r][jq * 4];
    float4 s;
    s.x = (s0.x + s1.x) + (s2.x + s3.x);
    s.y = (s0.y + s1.y) + (s2.y + s3.y);
    s.z = (s0.z + s1.z) + (s2.z + s3.z);
    s.w = (s0.w + s1.w) + (s2.w + s3.w);
    int orow = blockIdx.x * GR2 + r;
    if (orow < N) {
      float di = dinv[orow];
      s.x *= di; s.y *= di; s.z *= di; s.w *= di;
      *(float4*)&h1s[(size_t)orow * HID + jq * 4] = s;
    }
  }
}

// ===== layer1 aggregation + relu + W2, fused. 16 lanes per node. =====
__global__ __launch_bounds__(256) void k_agg1f(const int* __restrict__ rowbeg,
                                               const int* __restrict__ rowend,
                                               const int* __restrict__ csr,
                                               const float* __restrict__ h1s,
                                               const float* __restrict__ dinv,
                                               const float* __restrict__ b1,
                                               const float* __restrict__ W2,
                                               float* __restrict__ h2s, int N) {
  const int f = threadIdx.x & 15;
  const int node = blockIdx.x * 16 + (threadIdx.x >> 4);
  if (node >= N) return;
  int j = rowbeg[node];
  const int end = rowend[node];
  float acc = h1s[(size_t)node * HID + f];  // self loop (pre-scaled)
  for (; j < end && (j & 3); ++j) acc += h1s[(size_t)csr[j] * HID + f];
  for (; j + 4 <= end; j += 4) {
    int4 ss = *(const int4*)&csr[j];  // broadcast within group
    float a0 = h1s[(size_t)ss.x * HID + f];
    float a1 = h1s[(size_t)ss.y * HID + f];
    float a2 = h1s[(size_t)ss.z * HID + f];
    float a3 = h1s[(size_t)ss.w * HID + f];
    acc += (a0 + a1) + (a2 + a3);
  }
  for (; j < end; ++j) acc += h1s[(size_t)csr[j] * HID + f];

  float di = dinv[node];
  float v = fmaxf(acc * di + b1[f], 0.f);
  float o0 = v * W2[f * 2 + 0];
  float o1 = v * W2[f * 2 + 1];
#pragma unroll
  for (int d = 1; d < 16; d <<= 1) {
    o0 += __shfl_xor(o0, d);
    o1 += __shfl_xor(o1, d);
  }
  if (f == 0) *(float2*)&h2s[(size_t)node * 2] = make_float2(o0 * di, o1 * di);
}

// ===== layer2 aggregation + bias, fused. thread per node. =====
__global__ __launch_bounds__(256) void k_agg2f(const int* __restrict__ rowbeg,
                                               const int* __restrict__ rowend,
                                               const int* __restrict__ csr,
                                               const float* __restrict__ h2s,
                                               const float* __restrict__ dinv,
                                               const float* __restrict__ b2,
                                               float* __restrict__ out, int N) {
  int i = blockIdx.x * 256 + threadIdx.x;
  if (i >= N) return;
  int j = rowbeg[i];
  const int end = rowend[i];
  float2 o = *(const float2*)&h2s[(size_t)i * 2];  // self loop
  for (; j < end && (j & 3); ++j) {
    float2 v = *(const float2*)&h2s[(size_t)csr[j] * 2];
    o.x += v.x; o.y += v.y;
  }
  for (; j + 4 <= end; j += 4) {
    int4 ss = *(const int4*)&csr[j];
    float2 v0 = *(const float2*)&h2s[(size_t)ss.x * 2];
    float2 v1 = *(const float2*)&h2s[(size_t)ss.y * 2];
    float2 v2 = *(const float2*)&h2s[(size_t)ss.z * 2];
    float2 v3 = *(const float2*)&h2s[(size_t)ss.w * 2];
    o.x += (v0.x + v1.x) + (v2.x + v3.x);
    o.y += (v0.y + v1.y) + (v2.y + v3.y);
  }
  for (; j < end; ++j) {
    float2 v = *(const float2*)&h2s[(size_t)csr[j] * 2];
    o.x += v.x; o.y += v.y;
  }
  float di = dinv[i];
  o.x = o.x * di + b2[0];
  o.y = o.y * di + b2[1];
  *(float2*)&out[(size_t)i * 2] = o;
}

// ================= launch =================
extern "C" void kernel_launch(void* const* d_in, const int* in_sizes, int n_in,
                              void* d_out, int out_size, void* d_ws, size_t ws_size,
                              hipStream_t stream) {
  const float* x = (const float*)d_in[0];
  const int* ei = (const int*)d_in[1];  // harness delivers integer inputs as int32
  const float* W1 = (const float*)d_in[2];
  const float* b1 = (const float*)d_in[3];
  const float* W2 = (const float*)d_in[4];
  const float* b2 = (const float*)d_in[5];
  float* out = (float*)d_out;
  const int N = in_sizes[0] / NFEAT;
  const int E = in_sizes[1] / 2;
  const int nb = (N + 255) / 256;  // buckets of 256 nodes

  char* p = (char*)d_ws;
  int* cnt_t = (int*)p;    p += (size_t)MAXNB * NBLK * 4;
  int* off_t = (int*)p;    p += (size_t)MAXNB * NBLK * 4;
  int* gcnt = (int*)p;     p += (size_t)MAXNB * 4;
  int* gbase = (int*)p;    p += (size_t)MAXNB * 4;
  int* binned = (int*)p;   p += ((size_t)E + MAXNB * 16) * 4;
  int* csr = (int*)p;      p += ((size_t)E + MAXNB * 16) * 4;
  int* rowbeg = (int*)p;   p += (size_t)N * 4;
  int* rowend = (int*)p;   p += (size_t)N * 4;
  float* dinv = (float*)p; p += (size_t)N * 4;
  float* h1s = (float*)p;  p += (size_t)N * HID * 4;
  float* h2s = (float*)p;  p += (size_t)N * 2 * 4;

  k_hist2d<<<NBLK, 512, 0, stream>>>(ei, cnt_t, E, nb);
  k_colscan<<<nb, 64, 0, stream>>>(cnt_t, off_t, gcnt, nb);
  k_bscan<<<1, 512, 0, stream>>>(gcnt, gbase, nb);
  k_scatter2<<<NBLK, 512, 0, stream>>>(ei, gbase, off_t, binned, E, nb);
  k_sortbucket<<<nb, 256, 0, stream>>>(gbase, gcnt, binned, csr, rowbeg, rowend, dinv, N);
  k_gemm1<<<(N + GR2 - 1) / GR2, 256, 0, stream>>>(x, W1, dinv, h1s, N);
  k_agg1f<<<(N + 15) / 16, 256, 0, stream>>>(rowbeg, rowend, csr, h1s, dinv, b1, W2, h2s, N);
  k_agg2f<<<(N + 255) / 256, 256, 0, stream>>>(rowbeg, rowend, csr, h2s, dinv, b2, out, N);
}

// Round 12
// 188.952 us; speedup vs baseline: 1.2407x; 1.0779x over previous
//
#include <hip/hip_runtime.h>

#define NFEAT 512
#define HID 16
#define MAXNB 512          // max buckets (N/256 = 391 for N=100K)
#define NBLK 256           // blocks for hist/scatter passes (chunking must match)
#define PACK_SHIFT 17      // src fits in 17 bits (N < 131072)
#define PACK_MASK ((1 << PACK_SHIFT) - 1)

typedef _Float16 f16x8 __attribute__((ext_vector_type(8)));
typedef float f32x4 __attribute__((ext_vector_type(4)));

// ============ pass A: per-(block,bucket) histogram ============
__global__ __launch_bounds__(512) void k_hist2d(const int* __restrict__ ei,
                                                int* __restrict__ cnt_t,
                                                int E, int nb) {
  __shared__ int l[MAXNB];
  for (int i = threadIdx.x; i < nb; i += 512) l[i] = 0;
  __syncthreads();
  int chunk = (E + NBLK - 1) / NBLK;
  int beg = blockIdx.x * chunk;
  int end = beg + chunk; if (end > E) end = E;
  for (int e = beg + threadIdx.x; e < end; e += 512)
    atomicAdd(&l[ei[(size_t)E + e] >> 8], 1);
  __syncthreads();
  for (int b = threadIdx.x; b < nb; b += 512)
    cnt_t[(size_t)b * NBLK + blockIdx.x] = l[b];
}

// ============ per-bucket column scan (one wave per bucket) ============
__global__ __launch_bounds__(64) void k_colscan(const int* __restrict__ cnt_t,
                                                int* __restrict__ off_t,
                                                int* __restrict__ gcnt, int nb) {
  int b = blockIdx.x;
  if (b >= nb) return;
  int lane = threadIdx.x;
  int4 v = *(const int4*)&cnt_t[(size_t)b * NBLK + lane * 4];
  int tot = v.x + v.y + v.z + v.w;
  int s = tot;
  for (int d = 1; d < 64; d <<= 1) {
    int o = __shfl_up(s, d);
    if (lane >= d) s += o;
  }
  int excl = s - tot;
  int4 w;
  w.x = excl;
  w.y = excl + v.x;
  w.z = excl + v.x + v.y;
  w.w = excl + v.x + v.y + v.z;
  *(int4*)&off_t[(size_t)b * NBLK + lane * 4] = w;
  if (lane == 63) gcnt[b] = s;
}

// ============ scan: 16-aligned bucket bases ============
__global__ __launch_bounds__(512) void k_bscan(const int* __restrict__ gcnt,
                                               int* __restrict__ gbase, int nb) {
  __shared__ int sm[512];
  int t = threadIdx.x;
  int c = (t < nb) ? gcnt[t] : 0;
  int pc = (c + 15) & ~15;
  sm[t] = pc;
  __syncthreads();
  for (int off = 1; off < 512; off <<= 1) {
    int x = (t >= off) ? sm[t - off] : 0;
    __syncthreads();
    sm[t] += x;
    __syncthreads();
  }
  if (t < nb) gbase[t] = sm[t] - pc;
}

// ============ pass B: scatter with precomputed deterministic offsets ============
__global__ __launch_bounds__(512) void k_scatter2(const int* __restrict__ ei,
                                                  const int* __restrict__ gbase,
                                                  const int* __restrict__ off_t,
                                                  int* __restrict__ binned,
                                                  int E, int nb) {
  __shared__ int cur[MAXNB];
  for (int b = threadIdx.x; b < nb; b += 512)
    cur[b] = gbase[b] + off_t[(size_t)b * NBLK + blockIdx.x];
  __syncthreads();
  int chunk = (E + NBLK - 1) / NBLK;
  int beg = blockIdx.x * chunk;
  int end = beg + chunk; if (end > E) end = E;
  for (int e = beg + threadIdx.x; e < end; e += 512) {
    int s = ei[e];
    int d = ei[(size_t)E + e];
    int b = d >> 8;
    int pos = atomicAdd(&cur[b], 1);
    binned[pos] = s | ((d & 255) << PACK_SHIFT);
  }
}

// ============ per-bucket sort -> per-node CSR + dinv ============
__global__ __launch_bounds__(256) void k_sortbucket(const int* __restrict__ gbase,
                                                    const int* __restrict__ gcnt,
                                                    const int* __restrict__ binned,
                                                    int* __restrict__ csr,
                                                    int* __restrict__ rowbeg,
                                                    int* __restrict__ rowend,
                                                    float* __restrict__ dinv, int N) {
  __shared__ int hist[256];
  __shared__ int sm[256];
  __shared__ int cur[256];
  const int t = threadIdx.x;
  const int b = blockIdx.x;
  const int base = gbase[b], cnt = gcnt[b];
  hist[t] = 0;
  __syncthreads();
  for (int j = base + t; j < base + cnt; j += 256)
    atomicAdd(&hist[binned[j] >> PACK_SHIFT], 1);
  __syncthreads();
  int h = hist[t];
  sm[t] = h;
  __syncthreads();
  for (int off = 1; off < 256; off <<= 1) {
    int x = (t >= off) ? sm[t - off] : 0;
    __syncthreads();
    sm[t] += x;
    __syncthreads();
  }
  int incl = sm[t];
  int excl = incl - h;
  cur[t] = excl;
  int node = b * 256 + t;
  if (node < N) {
    rowbeg[node] = base + excl;
    rowend[node] = base + incl;
    dinv[node] = rsqrtf((float)h + 1.0f);
  }
  __syncthreads();
  for (int j = base + t; j < base + cnt; j += 256) {
    int val = binned[j];
    int pos = atomicAdd(&cur[val >> PACK_SHIFT], 1);
    csr[base + pos] = val & PACK_MASK;
  }
}

// ============ GEMM1 via MFMA fp16: h1s = (x @ W1) * dinv[row] ============
// Wave computes 16-row x 16-feat tiles with mfma_f32_16x16x32_f16.
// W held as 16 B-fragments in VGPRs (built once per wave, no LDS, no barriers).
// A-frag: lane holds x[row0 + (lane&15)][f*32 + (lane>>4)*8 + j], j=0..7.
// B-frag: lane holds W[f*32 + (lane>>4)*8 + j][lane&15].
// (Any consistent k-permutation cancels in the MFMA sum.)
// C/D: col = lane&15, row = (lane>>4)*4 + reg  [HW-verified layout].
__global__ __launch_bounds__(256) void k_gemm1(const float* __restrict__ x,
                                               const float* __restrict__ W,
                                               const float* __restrict__ dinv,
                                               float* __restrict__ h1s, int N) {
  const int wid = threadIdx.x >> 6;
  const int lane = threadIdx.x & 63;
  const int n = lane & 15;
  const int g = lane >> 4;

  // build B fragments (f16) from W (32 KB, L2-hot)
  f16x8 bf[16];
#pragma unroll
  for (int f = 0; f < 16; ++f) {
    const float* wp = W + (size_t)(f * 32 + g * 8) * HID + n;
#pragma unroll
    for (int j = 0; j < 8; ++j) bf[f][j] = (_Float16)wp[j * HID];
  }

  const int ntiles = (N + 15) >> 4;
  const int stride = gridDim.x * 4;
  for (int tile = blockIdx.x * 4 + wid; tile < ntiles; tile += stride) {
    int rowbase = tile * 16;
    if (rowbase + 16 > N) rowbase = N - 16;  // overlap-safe: rewrites same values
    const float* xr = x + (size_t)(rowbase + n) * NFEAT + g * 8;

    f32x4 acc = {0.f, 0.f, 0.f, 0.f};
#pragma unroll
    for (int f = 0; f < 16; ++f) {
      float4 p0 = *(const float4*)(xr + f * 32);
      float4 p1 = *(const float4*)(xr + f * 32 + 4);
      f16x8 af;
      af[0] = (_Float16)p0.x; af[1] = (_Float16)p0.y;
      af[2] = (_Float16)p0.z; af[3] = (_Float16)p0.w;
      af[4] = (_Float16)p1.x; af[5] = (_Float16)p1.y;
      af[6] = (_Float16)p1.z; af[7] = (_Float16)p1.w;
      acc = __builtin_amdgcn_mfma_f32_16x16x32_f16(af, bf[f], acc, 0, 0, 0);
    }

#pragma unroll
    for (int r = 0; r < 4; ++r) {
      int row = rowbase + g * 4 + r;
      h1s[(size_t)row * HID + n] = acc[r] * dinv[row];
    }
  }
}

// ===== layer1 aggregation + relu + W2, fused. 16 lanes per node. =====
__global__ __launch_bounds__(256) void k_agg1f(const int* __restrict__ rowbeg,
                                               const int* __restrict__ rowend,
                                               const int* __restrict__ csr,
                                               const float* __restrict__ h1s,
                                               const float* __restrict__ dinv,
                                               const float* __restrict__ b1,
                                               const float* __restrict__ W2,
                                               float* __restrict__ h2s, int N) {
  const int f = threadIdx.x & 15;
  const int node = blockIdx.x * 16 + (threadIdx.x >> 4);
  if (node >= N) return;
  int j = rowbeg[node];
  const int end = rowend[node];
  float acc = h1s[(size_t)node * HID + f];  // self loop (pre-scaled)
  for (; j < end && (j & 3); ++j) acc += h1s[(size_t)csr[j] * HID + f];
  for (; j + 4 <= end; j += 4) {
    int4 ss = *(const int4*)&csr[j];  // broadcast within group
    float a0 = h1s[(size_t)ss.x * HID + f];
    float a1 = h1s[(size_t)ss.y * HID + f];
    float a2 = h1s[(size_t)ss.z * HID + f];
    float a3 = h1s[(size_t)ss.w * HID + f];
    acc += (a0 + a1) + (a2 + a3);
  }
  for (; j < end; ++j) acc += h1s[(size_t)csr[j] * HID + f];

  float di = dinv[node];
  float v = fmaxf(acc * di + b1[f], 0.f);
  float o0 = v * W2[f * 2 + 0];
  float o1 = v * W2[f * 2 + 1];
#pragma unroll
  for (int d = 1; d < 16; d <<= 1) {
    o0 += __shfl_xor(o0, d);
    o1 += __shfl_xor(o1, d);
  }
  if (f == 0) *(float2*)&h2s[(size_t)node * 2] = make_float2(o0 * di, o1 * di);
}

// ===== layer2 aggregation + bias, fused. thread per node. =====
__global__ __launch_bounds__(256) void k_agg2f(const int* __restrict__ rowbeg,
                                               const int* __restrict__ rowend,
                                               const int* __restrict__ csr,
                                               const float* __restrict__ h2s,
                                               const float* __restrict__ dinv,
                                               const float* __restrict__ b2,
                                               float* __restrict__ out, int N) {
  int i = blockIdx.x * 256 + threadIdx.x;
  if (i >= N) return;
  int j = rowbeg[i];
  const int end = rowend[i];
  float2 o = *(const float2*)&h2s[(size_t)i * 2];  // self loop
  for (; j < end && (j & 3); ++j) {
    float2 v = *(const float2*)&h2s[(size_t)csr[j] * 2];
    o.x += v.x; o.y += v.y;
  }
  for (; j + 4 <= end; j += 4) {
    int4 ss = *(const int4*)&csr[j];
    float2 v0 = *(const float2*)&h2s[(size_t)ss.x * 2];
    float2 v1 = *(const float2*)&h2s[(size_t)ss.y * 2];
    float2 v2 = *(const float2*)&h2s[(size_t)ss.z * 2];
    float2 v3 = *(const float2*)&h2s[(size_t)ss.w * 2];
    o.x += (v0.x + v1.x) + (v2.x + v3.x);
    o.y += (v0.y + v1.y) + (v2.y + v3.y);
  }
  for (; j < end; ++j) {
    float2 v = *(const float2*)&h2s[(size_t)csr[j] * 2];
    o.x += v.x; o.y += v.y;
  }
  float di = dinv[i];
  o.x = o.x * di + b2[0];
  o.y = o.y * di + b2[1];
  *(float2*)&out[(size_t)i * 2] = o;
}

// ================= launch =================
extern "C" void kernel_launch(void* const* d_in, const int* in_sizes, int n_in,
                              void* d_out, int out_size, void* d_ws, size_t ws_size,
                              hipStream_t stream) {
  const float* x = (const float*)d_in[0];
  const int* ei = (const int*)d_in[1];  // harness delivers integer inputs as int32
  const float* W1 = (const float*)d_in[2];
  const float* b1 = (const float*)d_in[3];
  const float* W2 = (const float*)d_in[4];
  const float* b2 = (const float*)d_in[5];
  float* out = (float*)d_out;
  const int N = in_sizes[0] / NFEAT;
  const int E = in_sizes[1] / 2;
  const int nb = (N + 255) / 256;  // buckets of 256 nodes

  char* p = (char*)d_ws;
  int* cnt_t = (int*)p;    p += (size_t)MAXNB * NBLK * 4;
  int* off_t = (int*)p;    p += (size_t)MAXNB * NBLK * 4;
  int* gcnt = (int*)p;     p += (size_t)MAXNB * 4;
  int* gbase = (int*)p;    p += (size_t)MAXNB * 4;
  int* binned = (int*)p;   p += ((size_t)E + MAXNB * 16) * 4;
  int* csr = (int*)p;      p += ((size_t)E + MAXNB * 16) * 4;
  int* rowbeg = (int*)p;   p += (size_t)N * 4;
  int* rowend = (int*)p;   p += (size_t)N * 4;
  float* dinv = (float*)p; p += (size_t)N * 4;
  float* h1s = (float*)p;  p += (size_t)N * HID * 4;
  float* h2s = (float*)p;  p += (size_t)N * 2 * 4;

  const int ntiles = (N + 15) / 16;
  const int gblocks = (ntiles + 15) / 16;  // 4 waves x ~4 tiles each

  k_hist2d<<<NBLK, 512, 0, stream>>>(ei, cnt_t, E, nb);
  k_colscan<<<nb, 64, 0, stream>>>(cnt_t, off_t, gcnt, nb);
  k_bscan<<<1, 512, 0, stream>>>(gcnt, gbase, nb);
  k_scatter2<<<NBLK, 512, 0, stream>>>(ei, gbase, off_t, binned, E, nb);
  k_sortbucket<<<nb, 256, 0, stream>>>(gbase, gcnt, binned, csr, rowbeg, rowend, dinv, N);
  k_gemm1<<<gblocks, 256, 0, stream>>>(x, W1, dinv, h1s, N);
  k_agg1f<<<(N + 15) / 16, 256, 0, stream>>>(rowbeg, rowend, csr, h1s, dinv, b1, W2, h2s, N);
  k_agg2f<<<(N + 255) / 256, 256, 0, stream>>>(rowbeg, rowend, csr, h2s, dinv, b2, out, N);
}

// Round 13
// 185.622 us; speedup vs baseline: 1.2629x; 1.0179x over previous
//
#include <hip/hip_runtime.h>

#define NFEAT 512
#define HID 16
#define MAXNB 512          // max buckets (N/256 = 391 for N=100K)
#define NBLK 256           // blocks for hist/scatter passes (chunking must match)
#define PACK_SHIFT 17      // src fits in 17 bits (N < 131072)
#define PACK_MASK ((1 << PACK_SHIFT) - 1)

typedef _Float16 f16x8 __attribute__((ext_vector_type(8)));
typedef float f32x4 __attribute__((ext_vector_type(4)));

// ============ pass A: per-(block,bucket) histogram ============
__global__ __launch_bounds__(512) void k_hist2d(const int* __restrict__ ei,
                                                int* __restrict__ cnt_t,
                                                int E, int nb) {
  __shared__ int l[MAXNB];
  for (int i = threadIdx.x; i < nb; i += 512) l[i] = 0;
  __syncthreads();
  int chunk = (E + NBLK - 1) / NBLK;
  int beg = blockIdx.x * chunk;
  int end = beg + chunk; if (end > E) end = E;
  for (int e = beg + threadIdx.x; e < end; e += 512)
    atomicAdd(&l[ei[(size_t)E + e] >> 8], 1);
  __syncthreads();
  for (int b = threadIdx.x; b < nb; b += 512)
    cnt_t[(size_t)b * NBLK + blockIdx.x] = l[b];
}

// ============ per-bucket column scan (one wave per bucket) ============
__global__ __launch_bounds__(64) void k_colscan(const int* __restrict__ cnt_t,
                                                int* __restrict__ off_t,
                                                int* __restrict__ gcnt, int nb) {
  int b = blockIdx.x;
  if (b >= nb) return;
  int lane = threadIdx.x;
  int4 v = *(const int4*)&cnt_t[(size_t)b * NBLK + lane * 4];
  int tot = v.x + v.y + v.z + v.w;
  int s = tot;
  for (int d = 1; d < 64; d <<= 1) {
    int o = __shfl_up(s, d);
    if (lane >= d) s += o;
  }
  int excl = s - tot;
  int4 w;
  w.x = excl;
  w.y = excl + v.x;
  w.z = excl + v.x + v.y;
  w.w = excl + v.x + v.y + v.z;
  *(int4*)&off_t[(size_t)b * NBLK + lane * 4] = w;
  if (lane == 63) gcnt[b] = s;
}

// ============ scan: 16-aligned bucket bases ============
__global__ __launch_bounds__(512) void k_bscan(const int* __restrict__ gcnt,
                                               int* __restrict__ gbase, int nb) {
  __shared__ int sm[512];
  int t = threadIdx.x;
  int c = (t < nb) ? gcnt[t] : 0;
  int pc = (c + 15) & ~15;
  sm[t] = pc;
  __syncthreads();
  for (int off = 1; off < 512; off <<= 1) {
    int x = (t >= off) ? sm[t - off] : 0;
    __syncthreads();
    sm[t] += x;
    __syncthreads();
  }
  if (t < nb) gbase[t] = sm[t] - pc;
}

// ============ pass B: scatter with precomputed deterministic offsets ============
__global__ __launch_bounds__(512) void k_scatter2(const int* __restrict__ ei,
                                                  const int* __restrict__ gbase,
                                                  const int* __restrict__ off_t,
                                                  int* __restrict__ binned,
                                                  int E, int nb) {
  __shared__ int cur[MAXNB];
  for (int b = threadIdx.x; b < nb; b += 512)
    cur[b] = gbase[b] + off_t[(size_t)b * NBLK + blockIdx.x];
  __syncthreads();
  int chunk = (E + NBLK - 1) / NBLK;
  int beg = blockIdx.x * chunk;
  int end = beg + chunk; if (end > E) end = E;
  for (int e = beg + threadIdx.x; e < end; e += 512) {
    int s = ei[e];
    int d = ei[(size_t)E + e];
    int b = d >> 8;
    int pos = atomicAdd(&cur[b], 1);
    binned[pos] = s | ((d & 255) << PACK_SHIFT);
  }
}

// ============ per-bucket sort -> per-node CSR + dinv ============
__global__ __launch_bounds__(256) void k_sortbucket(const int* __restrict__ gbase,
                                                    const int* __restrict__ gcnt,
                                                    const int* __restrict__ binned,
                                                    int* __restrict__ csr,
                                                    int* __restrict__ rowbeg,
                                                    int* __restrict__ rowend,
                                                    float* __restrict__ dinv, int N) {
  __shared__ int hist[256];
  __shared__ int sm[256];
  __shared__ int cur[256];
  const int t = threadIdx.x;
  const int b = blockIdx.x;
  const int base = gbase[b], cnt = gcnt[b];
  hist[t] = 0;
  __syncthreads();
  for (int j = base + t; j < base + cnt; j += 256)
    atomicAdd(&hist[binned[j] >> PACK_SHIFT], 1);
  __syncthreads();
  int h = hist[t];
  sm[t] = h;
  __syncthreads();
  for (int off = 1; off < 256; off <<= 1) {
    int x = (t >= off) ? sm[t - off] : 0;
    __syncthreads();
    sm[t] += x;
    __syncthreads();
  }
  int incl = sm[t];
  int excl = incl - h;
  cur[t] = excl;
  int node = b * 256 + t;
  if (node < N) {
    rowbeg[node] = base + excl;
    rowend[node] = base + incl;
    dinv[node] = rsqrtf((float)h + 1.0f);
  }
  __syncthreads();
  for (int j = base + t; j < base + cnt; j += 256) {
    int val = binned[j];
    int pos = atomicAdd(&cur[val >> PACK_SHIFT], 1);
    csr[base + pos] = val & PACK_MASK;
  }
}

// ============ GEMM1 via MFMA fp16: h1s = (x @ W1) * dinv[row] ============
// ONE 16-row x 16-feat tile PER WAVE (1563 blocks, ~24 waves/CU) — the 4-tile
// serial loop was latency-starved at 391 blocks.
// W held as 16 B-fragments in VGPRs (no LDS, no barriers).
// A-frag: lane holds x[row0 + (lane&15)][f*32 + (lane>>4)*8 + j], j=0..7.
// B-frag: lane holds W[f*32 + (lane>>4)*8 + j][lane&15]. (Consistent
// k-permutation cancels in the MFMA sum.)
// C/D: col = lane&15, row = (lane>>4)*4 + reg  [HW-verified layout].
__global__ __launch_bounds__(256) void k_gemm1(const float* __restrict__ x,
                                               const float* __restrict__ W,
                                               const float* __restrict__ dinv,
                                               float* __restrict__ h1s, int N) {
  const int wid = threadIdx.x >> 6;
  const int lane = threadIdx.x & 63;
  const int n = lane & 15;
  const int g = lane >> 4;

  const int ntiles = (N + 15) >> 4;
  const int tile = blockIdx.x * 4 + wid;
  if (tile >= ntiles) return;

  // build B fragments (f16) from W (32 KB, L1/L2-hot)
  f16x8 bf[16];
#pragma unroll
  for (int f = 0; f < 16; ++f) {
    const float* wp = W + (size_t)(f * 32 + g * 8) * HID + n;
#pragma unroll
    for (int j = 0; j < 8; ++j) bf[f][j] = (_Float16)wp[j * HID];
  }

  int rowbase = tile * 16;
  if (rowbase + 16 > N) rowbase = N - 16;  // overlap-safe: rewrites same values
  const float* xr = x + (size_t)(rowbase + n) * NFEAT + g * 8;

  f32x4 acc = {0.f, 0.f, 0.f, 0.f};
#pragma unroll
  for (int f = 0; f < 16; ++f) {
    float4 p0 = *(const float4*)(xr + f * 32);
    float4 p1 = *(const float4*)(xr + f * 32 + 4);
    f16x8 af;
    af[0] = (_Float16)p0.x; af[1] = (_Float16)p0.y;
    af[2] = (_Float16)p0.z; af[3] = (_Float16)p0.w;
    af[4] = (_Float16)p1.x; af[5] = (_Float16)p1.y;
    af[6] = (_Float16)p1.z; af[7] = (_Float16)p1.w;
    acc = __builtin_amdgcn_mfma_f32_16x16x32_f16(af, bf[f], acc, 0, 0, 0);
  }

#pragma unroll
  for (int r = 0; r < 4; ++r) {
    int row = rowbase + g * 4 + r;
    h1s[(size_t)row * HID + n] = acc[r] * dinv[row];
  }
}

// ===== layer1 aggregation + relu + W2, fused. 16 lanes per node. =====
__global__ __launch_bounds__(256) void k_agg1f(const int* __restrict__ rowbeg,
                                               const int* __restrict__ rowend,
                                               const int* __restrict__ csr,
                                               const float* __restrict__ h1s,
                                               const float* __restrict__ dinv,
                                               const float* __restrict__ b1,
                                               const float* __restrict__ W2,
                                               float* __restrict__ h2s, int N) {
  const int f = threadIdx.x & 15;
  const int node = blockIdx.x * 16 + (threadIdx.x >> 4);
  if (node >= N) return;
  int j = rowbeg[node];
  const int end = rowend[node];
  float acc = h1s[(size_t)node * HID + f];  // self loop (pre-scaled)
  for (; j < end && (j & 3); ++j) acc += h1s[(size_t)csr[j] * HID + f];
  for (; j + 4 <= end; j += 4) {
    int4 ss = *(const int4*)&csr[j];  // broadcast within group
    float a0 = h1s[(size_t)ss.x * HID + f];
    float a1 = h1s[(size_t)ss.y * HID + f];
    float a2 = h1s[(size_t)ss.z * HID + f];
    float a3 = h1s[(size_t)ss.w * HID + f];
    acc += (a0 + a1) + (a2 + a3);
  }
  for (; j < end; ++j) acc += h1s[(size_t)csr[j] * HID + f];

  float di = dinv[node];
  float v = fmaxf(acc * di + b1[f], 0.f);
  float o0 = v * W2[f * 2 + 0];
  float o1 = v * W2[f * 2 + 1];
#pragma unroll
  for (int d = 1; d < 16; d <<= 1) {
    o0 += __shfl_xor(o0, d);
    o1 += __shfl_xor(o1, d);
  }
  if (f == 0) *(float2*)&h2s[(size_t)node * 2] = make_float2(o0 * di, o1 * di);
}

// ===== layer2 aggregation + bias, fused. thread per node. =====
__global__ __launch_bounds__(256) void k_agg2f(const int* __restrict__ rowbeg,
                                               const int* __restrict__ rowend,
                                               const int* __restrict__ csr,
                                               const float* __restrict__ h2s,
                                               const float* __restrict__ dinv,
                                               const float* __restrict__ b2,
                                               float* __restrict__ out, int N) {
  int i = blockIdx.x * 256 + threadIdx.x;
  if (i >= N) return;
  int j = rowbeg[i];
  const int end = rowend[i];
  float2 o = *(const float2*)&h2s[(size_t)i * 2];  // self loop
  for (; j < end && (j & 3); ++j) {
    float2 v = *(const float2*)&h2s[(size_t)csr[j] * 2];
    o.x += v.x; o.y += v.y;
  }
  for (; j + 4 <= end; j += 4) {
    int4 ss = *(const int4*)&csr[j];
    float2 v0 = *(const float2*)&h2s[(size_t)ss.x * 2];
    float2 v1 = *(const float2*)&h2s[(size_t)ss.y * 2];
    float2 v2 = *(const float2*)&h2s[(size_t)ss.z * 2];
    float2 v3 = *(const float2*)&h2s[(size_t)ss.w * 2];
    o.x += (v0.x + v1.x) + (v2.x + v3.x);
    o.y += (v0.y + v1.y) + (v2.y + v3.y);
  }
  for (; j < end; ++j) {
    float2 v = *(const float2*)&h2s[(size_t)csr[j] * 2];
    o.x += v.x; o.y += v.y;
  }
  float di = dinv[i];
  o.x = o.x * di + b2[0];
  o.y = o.y * di + b2[1];
  *(float2*)&out[(size_t)i * 2] = o;
}

// ================= launch =================
extern "C" void kernel_launch(void* const* d_in, const int* in_sizes, int n_in,
                              void* d_out, int out_size, void* d_ws, size_t ws_size,
                              hipStream_t stream) {
  const float* x = (const float*)d_in[0];
  const int* ei = (const int*)d_in[1];  // harness delivers integer inputs as int32
  const float* W1 = (const float*)d_in[2];
  const float* b1 = (const float*)d_in[3];
  const float* W2 = (const float*)d_in[4];
  const float* b2 = (const float*)d_in[5];
  float* out = (float*)d_out;
  const int N = in_sizes[0] / NFEAT;
  const int E = in_sizes[1] / 2;
  const int nb = (N + 255) / 256;  // buckets of 256 nodes

  char* p = (char*)d_ws;
  int* cnt_t = (int*)p;    p += (size_t)MAXNB * NBLK * 4;
  int* off_t = (int*)p;    p += (size_t)MAXNB * NBLK * 4;
  int* gcnt = (int*)p;     p += (size_t)MAXNB * 4;
  int* gbase = (int*)p;    p += (size_t)MAXNB * 4;
  int* binned = (int*)p;   p += ((size_t)E + MAXNB * 16) * 4;
  int* csr = (int*)p;      p += ((size_t)E + MAXNB * 16) * 4;
  int* rowbeg = (int*)p;   p += (size_t)N * 4;
  int* rowend = (int*)p;   p += (size_t)N * 4;
  float* dinv = (float*)p; p += (size_t)N * 4;
  float* h1s = (float*)p;  p += (size_t)N * HID * 4;
  float* h2s = (float*)p;  p += (size_t)N * 2 * 4;

  const int ntiles = (N + 15) / 16;
  const int gblocks = (ntiles + 3) / 4;  // ONE tile per wave

  k_hist2d<<<NBLK, 512, 0, stream>>>(ei, cnt_t, E, nb);
  k_colscan<<<nb, 64, 0, stream>>>(cnt_t, off_t, gcnt, nb);
  k_bscan<<<1, 512, 0, stream>>>(gcnt, gbase, nb);
  k_scatter2<<<NBLK, 512, 0, stream>>>(ei, gbase, off_t, binned, E, nb);
  k_sortbucket<<<nb, 256, 0, stream>>>(gbase, gcnt, binned, csr, rowbeg, rowend, dinv, N);
  k_gemm1<<<gblocks, 256, 0, stream>>>(x, W1, dinv, h1s, N);
  k_agg1f<<<(N + 15) / 16, 256, 0, stream>>>(rowbeg, rowend, csr, h1s, dinv, b1, W2, h2s, N);
  k_agg2f<<<(N + 255) / 256, 256, 0, stream>>>(rowbeg, rowend, csr, h2s, dinv, b2, out, N);
}

// Round 14
// 177.991 us; speedup vs baseline: 1.3171x; 1.0429x over previous
//
#include <hip/hip_runtime.h>
#include <hip/hip_fp16.h>

#define NFEAT 512
#define HID 16
#define MAXNB 512          // max buckets (N/256 = 391 for N=100K)
#define NBLK 512           // blocks for hist/scatter passes (chunking must match)
#define PACK_SHIFT 17      // src fits in 17 bits (N < 131072)
#define PACK_MASK ((1 << PACK_SHIFT) - 1)

typedef _Float16 f16x8 __attribute__((ext_vector_type(8)));
typedef float f32x4 __attribute__((ext_vector_type(4)));

// ============ pass A: per-(block,bucket) histogram ============
__global__ __launch_bounds__(512) void k_hist2d(const int* __restrict__ ei,
                                                int* __restrict__ cnt_t,
                                                int E, int nb) {
  __shared__ int l[MAXNB];
  for (int i = threadIdx.x; i < nb; i += 512) l[i] = 0;
  __syncthreads();
  int chunk = (E + NBLK - 1) / NBLK;
  int beg = blockIdx.x * chunk;
  int end = beg + chunk; if (end > E) end = E;
  for (int e = beg + threadIdx.x; e < end; e += 512)
    atomicAdd(&l[ei[(size_t)E + e] >> 8], 1);
  __syncthreads();
  for (int b = threadIdx.x; b < nb; b += 512)
    cnt_t[(size_t)b * NBLK + blockIdx.x] = l[b];
}

// ============ per-bucket column scan (one wave per bucket, 8 counts/lane) ====
__global__ __launch_bounds__(64) void k_colscan(const int* __restrict__ cnt_t,
                                                int* __restrict__ off_t,
                                                int* __restrict__ gcnt, int nb) {
  int b = blockIdx.x;
  if (b >= nb) return;
  int lane = threadIdx.x;
  int4 v0 = *(const int4*)&cnt_t[(size_t)b * NBLK + lane * 8];
  int4 v1 = *(const int4*)&cnt_t[(size_t)b * NBLK + lane * 8 + 4];
  int tot = (v0.x + v0.y + v0.z + v0.w) + (v1.x + v1.y + v1.z + v1.w);
  int s = tot;
  for (int d = 1; d < 64; d <<= 1) {
    int o = __shfl_up(s, d);
    if (lane >= d) s += o;
  }
  int excl = s - tot;
  int4 w0, w1;
  w0.x = excl;
  w0.y = w0.x + v0.x;
  w0.z = w0.y + v0.y;
  w0.w = w0.z + v0.z;
  w1.x = w0.w + v0.w;
  w1.y = w1.x + v1.x;
  w1.z = w1.y + v1.y;
  w1.w = w1.z + v1.z;
  *(int4*)&off_t[(size_t)b * NBLK + lane * 8] = w0;
  *(int4*)&off_t[(size_t)b * NBLK + lane * 8 + 4] = w1;
  if (lane == 63) gcnt[b] = s;
}

// ============ scan: 16-aligned bucket bases ============
__global__ __launch_bounds__(512) void k_bscan(const int* __restrict__ gcnt,
                                               int* __restrict__ gbase, int nb) {
  __shared__ int sm[512];
  int t = threadIdx.x;
  int c = (t < nb) ? gcnt[t] : 0;
  int pc = (c + 15) & ~15;
  sm[t] = pc;
  __syncthreads();
  for (int off = 1; off < 512; off <<= 1) {
    int x = (t >= off) ? sm[t - off] : 0;
    __syncthreads();
    sm[t] += x;
    __syncthreads();
  }
  if (t < nb) gbase[t] = sm[t] - pc;
}

// ============ pass B: scatter with precomputed deterministic offsets ============
__global__ __launch_bounds__(512) void k_scatter2(const int* __restrict__ ei,
                                                  const int* __restrict__ gbase,
                                                  const int* __restrict__ off_t,
                                                  int* __restrict__ binned,
                                                  int E, int nb) {
  __shared__ int cur[MAXNB];
  for (int b = threadIdx.x; b < nb; b += 512)
    cur[b] = gbase[b] + off_t[(size_t)b * NBLK + blockIdx.x];
  __syncthreads();
  int chunk = (E + NBLK - 1) / NBLK;
  int beg = blockIdx.x * chunk;
  int end = beg + chunk; if (end > E) end = E;
  for (int e = beg + threadIdx.x; e < end; e += 512) {
    int s = ei[e];
    int d = ei[(size_t)E + e];
    int b = d >> 8;
    int pos = atomicAdd(&cur[b], 1);
    binned[pos] = s | ((d & 255) << PACK_SHIFT);
  }
}

// ============ per-bucket sort -> per-node CSR + dinv ============
__global__ __launch_bounds__(256) void k_sortbucket(const int* __restrict__ gbase,
                                                    const int* __restrict__ gcnt,
                                                    const int* __restrict__ binned,
                                                    int* __restrict__ csr,
                                                    int* __restrict__ rowbeg,
                                                    int* __restrict__ rowend,
                                                    float* __restrict__ dinv, int N) {
  __shared__ int hist[256];
  __shared__ int sm[256];
  __shared__ int cur[256];
  const int t = threadIdx.x;
  const int b = blockIdx.x;
  const int base = gbase[b], cnt = gcnt[b];
  hist[t] = 0;
  __syncthreads();
  for (int j = base + t; j < base + cnt; j += 256)
    atomicAdd(&hist[binned[j] >> PACK_SHIFT], 1);
  __syncthreads();
  int h = hist[t];
  sm[t] = h;
  __syncthreads();
  for (int off = 1; off < 256; off <<= 1) {
    int x = (t >= off) ? sm[t - off] : 0;
    __syncthreads();
    sm[t] += x;
    __syncthreads();
  }
  int incl = sm[t];
  int excl = incl - h;
  cur[t] = excl;
  int node = b * 256 + t;
  if (node < N) {
    rowbeg[node] = base + excl;
    rowend[node] = base + incl;
    dinv[node] = rsqrtf((float)h + 1.0f);
  }
  __syncthreads();
  for (int j = base + t; j < base + cnt; j += 256) {
    int val = binned[j];
    int pos = atomicAdd(&cur[val >> PACK_SHIFT], 1);
    csr[base + pos] = val & PACK_MASK;
  }
}

// ============ GEMM1 via MFMA fp16: h1h = fp16( (x @ W1) * dinv[row] ) ========
// One 16x16 tile per wave. W as 16 B-fragments in VGPRs (no LDS, no barriers).
// C/D: col = lane&15, row = (lane>>4)*4 + reg  [HW-verified layout].
__global__ __launch_bounds__(256) void k_gemm1(const float* __restrict__ x,
                                               const float* __restrict__ W,
                                               const float* __restrict__ dinv,
                                               __half* __restrict__ h1h, int N) {
  const int wid = threadIdx.x >> 6;
  const int lane = threadIdx.x & 63;
  const int n = lane & 15;
  const int g = lane >> 4;

  const int ntiles = (N + 15) >> 4;
  const int tile = blockIdx.x * 4 + wid;
  if (tile >= ntiles) return;

  f16x8 bf[16];
#pragma unroll
  for (int f = 0; f < 16; ++f) {
    const float* wp = W + (size_t)(f * 32 + g * 8) * HID + n;
#pragma unroll
    for (int j = 0; j < 8; ++j) bf[f][j] = (_Float16)wp[j * HID];
  }

  int rowbase = tile * 16;
  if (rowbase + 16 > N) rowbase = N - 16;  // overlap-safe: rewrites same values
  const float* xr = x + (size_t)(rowbase + n) * NFEAT + g * 8;

  f32x4 acc = {0.f, 0.f, 0.f, 0.f};
#pragma unroll
  for (int f = 0; f < 16; ++f) {
    float4 p0 = *(const float4*)(xr + f * 32);
    float4 p1 = *(const float4*)(xr + f * 32 + 4);
    f16x8 af;
    af[0] = (_Float16)p0.x; af[1] = (_Float16)p0.y;
    af[2] = (_Float16)p0.z; af[3] = (_Float16)p0.w;
    af[4] = (_Float16)p1.x; af[5] = (_Float16)p1.y;
    af[6] = (_Float16)p1.z; af[7] = (_Float16)p1.w;
    acc = __builtin_amdgcn_mfma_f32_16x16x32_f16(af, bf[f], acc, 0, 0, 0);
  }

#pragma unroll
  for (int r = 0; r < 4; ++r) {
    int row = rowbase + g * 4 + r;
    h1h[(size_t)row * HID + n] = __float2half(acc[r] * dinv[row]);
  }
}

// ===== layer1 aggregation + relu + W2, fused. 16 lanes per node, fp16 h1. =====
__global__ __launch_bounds__(256) void k_agg1f(const int* __restrict__ rowbeg,
                                               const int* __restrict__ rowend,
                                               const int* __restrict__ csr,
                                               const __half* __restrict__ h1h,
                                               const float* __restrict__ dinv,
                                               const float* __restrict__ b1,
                                               const float* __restrict__ W2,
                                               float* __restrict__ h2s, int N) {
  const int f = threadIdx.x & 15;
  const int node = blockIdx.x * 16 + (threadIdx.x >> 4);
  if (node >= N) return;
  int j = rowbeg[node];
  const int end = rowend[node];
  float acc = __half2float(h1h[(size_t)node * HID + f]);  // self loop (pre-scaled)
  for (; j < end && (j & 3); ++j) acc += __half2float(h1h[(size_t)csr[j] * HID + f]);
  for (; j + 4 <= end; j += 4) {
    int4 ss = *(const int4*)&csr[j];  // broadcast within group
    float a0 = __half2float(h1h[(size_t)ss.x * HID + f]);
    float a1 = __half2float(h1h[(size_t)ss.y * HID + f]);
    float a2 = __half2float(h1h[(size_t)ss.z * HID + f]);
    float a3 = __half2float(h1h[(size_t)ss.w * HID + f]);
    acc += (a0 + a1) + (a2 + a3);
  }
  for (; j < end; ++j) acc += __half2float(h1h[(size_t)csr[j] * HID + f]);

  float di = dinv[node];
  float v = fmaxf(acc * di + b1[f], 0.f);
  float o0 = v * W2[f * 2 + 0];
  float o1 = v * W2[f * 2 + 1];
#pragma unroll
  for (int d = 1; d < 16; d <<= 1) {
    o0 += __shfl_xor(o0, d);
    o1 += __shfl_xor(o1, d);
  }
  if (f == 0) *(float2*)&h2s[(size_t)node * 2] = make_float2(o0 * di, o1 * di);
}

// ===== layer2 aggregation + bias, fused. thread per node. =====
__global__ __launch_bounds__(256) void k_agg2f(const int* __restrict__ rowbeg,
                                               const int* __restrict__ rowend,
                                               const int* __restrict__ csr,
                                               const float* __restrict__ h2s,
                                               const float* __restrict__ dinv,
                                               const float* __restrict__ b2,
                                               float* __restrict__ out, int N) {
  int i = blockIdx.x * 256 + threadIdx.x;
  if (i >= N) return;
  int j = rowbeg[i];
  const int end = rowend[i];
  float2 o = *(const float2*)&h2s[(size_t)i * 2];  // self loop
  for (; j < end && (j & 3); ++j) {
    float2 v = *(const float2*)&h2s[(size_t)csr[j] * 2];
    o.x += v.x; o.y += v.y;
  }
  for (; j + 4 <= end; j += 4) {
    int4 ss = *(const int4*)&csr[j];
    float2 v0 = *(const float2*)&h2s[(size_t)ss.x * 2];
    float2 v1 = *(const float2*)&h2s[(size_t)ss.y * 2];
    float2 v2 = *(const float2*)&h2s[(size_t)ss.z * 2];
    float2 v3 = *(const float2*)&h2s[(size_t)ss.w * 2];
    o.x += (v0.x + v1.x) + (v2.x + v3.x);
    o.y += (v0.y + v1.y) + (v2.y + v3.y);
  }
  for (; j < end; ++j) {
    float2 v = *(const float2*)&h2s[(size_t)csr[j] * 2];
    o.x += v.x; o.y += v.y;
  }
  float di = dinv[i];
  o.x = o.x * di + b2[0];
  o.y = o.y * di + b2[1];
  *(float2*)&out[(size_t)i * 2] = o;
}

// ================= launch =================
extern "C" void kernel_launch(void* const* d_in, const int* in_sizes, int n_in,
                              void* d_out, int out_size, void* d_ws, size_t ws_size,
                              hipStream_t stream) {
  const float* x = (const float*)d_in[0];
  const int* ei = (const int*)d_in[1];  // harness delivers integer inputs as int32
  const float* W1 = (const float*)d_in[2];
  const float* b1 = (const float*)d_in[3];
  const float* W2 = (const float*)d_in[4];
  const float* b2 = (const float*)d_in[5];
  float* out = (float*)d_out;
  const int N = in_sizes[0] / NFEAT;
  const int E = in_sizes[1] / 2;
  const int nb = (N + 255) / 256;  // buckets of 256 nodes

  char* p = (char*)d_ws;
  int* cnt_t = (int*)p;    p += (size_t)MAXNB * NBLK * 4;
  int* off_t = (int*)p;    p += (size_t)MAXNB * NBLK * 4;
  int* gcnt = (int*)p;     p += (size_t)MAXNB * 4;
  int* gbase = (int*)p;    p += (size_t)MAXNB * 4;
  int* binned = (int*)p;   p += ((size_t)E + MAXNB * 16) * 4;
  int* csr = (int*)p;      p += ((size_t)E + MAXNB * 16) * 4;
  int* rowbeg = (int*)p;   p += (size_t)N * 4;
  int* rowend = (int*)p;   p += (size_t)N * 4;
  float* dinv = (float*)p; p += (size_t)N * 4;
  __half* h1h = (__half*)p; p += (size_t)N * HID * 2;
  float* h2s = (float*)p;  p += (size_t)N * 2 * 4;

  const int ntiles = (N + 15) / 16;
  const int gblocks = (ntiles + 3) / 4;  // one tile per wave

  k_hist2d<<<NBLK, 512, 0, stream>>>(ei, cnt_t, E, nb);
  k_colscan<<<nb, 64, 0, stream>>>(cnt_t, off_t, gcnt, nb);
  k_bscan<<<1, 512, 0, stream>>>(gcnt, gbase, nb);
  k_scatter2<<<NBLK, 512, 0, stream>>>(ei, gbase, off_t, binned, E, nb);
  k_sortbucket<<<nb, 256, 0, stream>>>(gbase, gcnt, binned, csr, rowbeg, rowend, dinv, N);
  k_gemm1<<<gblocks, 256, 0, stream>>>(x, W1, dinv, h1h, N);
  k_agg1f<<<(N + 15) / 16, 256, 0, stream>>>(rowbeg, rowend, csr, h1h, dinv, b1, W2, h2s, N);
  k_agg2f<<<(N + 255) / 256, 256, 0, stream>>>(rowbeg, rowend, csr, h2s, dinv, b2, out, N);
}

// Round 15
// 167.437 us; speedup vs baseline: 1.4001x; 1.0630x over previous
//
#include <hip/hip_runtime.h>
#include <hip/hip_fp16.h>

#define NFEAT 512
#define HID 16
#define MAXNB 512          // max buckets (N/256 = 391 for N=100K)
#define NBLK 512           // blocks for hist/scatter passes (chunking must match)
#define PACK_SHIFT 17      // src fits in 17 bits (N < 131072)
#define PACK_MASK ((1 << PACK_SHIFT) - 1)

typedef _Float16 f16x8 __attribute__((ext_vector_type(8)));
typedef float f32x4 __attribute__((ext_vector_type(4)));

// ============ pass A: per-(block,bucket) histogram ============
__global__ __launch_bounds__(512) void k_hist2d(const int* __restrict__ ei,
                                                int* __restrict__ cnt_t,
                                                int E, int nb) {
  __shared__ int l[MAXNB];
  for (int i = threadIdx.x; i < nb; i += 512) l[i] = 0;
  __syncthreads();
  int chunk = (E + NBLK - 1) / NBLK;
  int beg = blockIdx.x * chunk;
  int end = beg + chunk; if (end > E) end = E;
  for (int e = beg + threadIdx.x; e < end; e += 512)
    atomicAdd(&l[ei[(size_t)E + e] >> 8], 1);
  __syncthreads();
  for (int b = threadIdx.x; b < nb; b += 512)
    cnt_t[(size_t)b * NBLK + blockIdx.x] = l[b];
}

// ============ per-bucket column scan (one wave per bucket, 8 counts/lane) ====
__global__ __launch_bounds__(64) void k_colscan(const int* __restrict__ cnt_t,
                                                int* __restrict__ off_t,
                                                int* __restrict__ gcnt, int nb) {
  int b = blockIdx.x;
  if (b >= nb) return;
  int lane = threadIdx.x;
  int4 v0 = *(const int4*)&cnt_t[(size_t)b * NBLK + lane * 8];
  int4 v1 = *(const int4*)&cnt_t[(size_t)b * NBLK + lane * 8 + 4];
  int tot = (v0.x + v0.y + v0.z + v0.w) + (v1.x + v1.y + v1.z + v1.w);
  int s = tot;
  for (int d = 1; d < 64; d <<= 1) {
    int o = __shfl_up(s, d);
    if (lane >= d) s += o;
  }
  int excl = s - tot;
  int4 w0, w1;
  w0.x = excl;
  w0.y = w0.x + v0.x;
  w0.z = w0.y + v0.y;
  w0.w = w0.z + v0.z;
  w1.x = w0.w + v0.w;
  w1.y = w1.x + v1.x;
  w1.z = w1.y + v1.y;
  w1.w = w1.z + v1.z;
  *(int4*)&off_t[(size_t)b * NBLK + lane * 8] = w0;
  *(int4*)&off_t[(size_t)b * NBLK + lane * 8 + 4] = w1;
  if (lane == 63) gcnt[b] = s;
}

// ============ scan: 16-aligned bucket bases ============
__global__ __launch_bounds__(512) void k_bscan(const int* __restrict__ gcnt,
                                               int* __restrict__ gbase, int nb) {
  __shared__ int sm[512];
  int t = threadIdx.x;
  int c = (t < nb) ? gcnt[t] : 0;
  int pc = (c + 15) & ~15;
  sm[t] = pc;
  __syncthreads();
  for (int off = 1; off < 512; off <<= 1) {
    int x = (t >= off) ? sm[t - off] : 0;
    __syncthreads();
    sm[t] += x;
    __syncthreads();
  }
  if (t < nb) gbase[t] = sm[t] - pc;
}

// ============ pass B: scatter with precomputed deterministic offsets ============
__global__ __launch_bounds__(512) void k_scatter2(const int* __restrict__ ei,
                                                  const int* __restrict__ gbase,
                                                  const int* __restrict__ off_t,
                                                  int* __restrict__ binned,
                                                  int E, int nb) {
  __shared__ int cur[MAXNB];
  for (int b = threadIdx.x; b < nb; b += 512)
    cur[b] = gbase[b] + off_t[(size_t)b * NBLK + blockIdx.x];
  __syncthreads();
  int chunk = (E + NBLK - 1) / NBLK;
  int beg = blockIdx.x * chunk;
  int end = beg + chunk; if (end > E) end = E;
  for (int e = beg + threadIdx.x; e < end; e += 512) {
    int s = ei[e];
    int d = ei[(size_t)E + e];
    int b = d >> 8;
    int pos = atomicAdd(&cur[b], 1);
    binned[pos] = s | ((d & 255) << PACK_SHIFT);
  }
}

// ============ per-bucket sort -> per-node CSR + dinv (512 thr, 12 waves/CU) ====
__global__ __launch_bounds__(512) void k_sortbucket(const int* __restrict__ gbase,
                                                    const int* __restrict__ gcnt,
                                                    const int* __restrict__ binned,
                                                    int* __restrict__ csr,
                                                    int* __restrict__ rowbeg,
                                                    int* __restrict__ rowend,
                                                    float* __restrict__ dinv, int N) {
  __shared__ int hist[256];
  __shared__ int sm[256];
  __shared__ int cur[256];
  const int t = threadIdx.x;
  const int b = blockIdx.x;
  const int base = gbase[b], cnt = gcnt[b];
  if (t < 256) hist[t] = 0;
  __syncthreads();
  for (int j = base + t; j < base + cnt; j += 512)
    atomicAdd(&hist[binned[j] >> PACK_SHIFT], 1);
  __syncthreads();
  int h = 0;
  if (t < 256) {
    h = hist[t];
    sm[t] = h;
  }
  __syncthreads();
  for (int off = 1; off < 256; off <<= 1) {
    int x = 0;
    if (t < 256 && t >= off) x = sm[t - off];
    __syncthreads();
    if (t < 256) sm[t] += x;
    __syncthreads();
  }
  if (t < 256) {
    int incl = sm[t];
    int excl = incl - h;
    cur[t] = excl;
    int node = b * 256 + t;
    if (node < N) {
      rowbeg[node] = base + excl;
      rowend[node] = base + incl;
      dinv[node] = rsqrtf((float)h + 1.0f);
    }
  }
  __syncthreads();
  for (int j = base + t; j < base + cnt; j += 512) {
    int val = binned[j];
    int pos = atomicAdd(&cur[val >> PACK_SHIFT], 1);
    csr[base + pos] = val & PACK_MASK;
  }
}

// ============ GEMM1 via MFMA fp16: h1h = fp16( (x @ W1) * dinv[row] ) ========
// One 16x16 tile per wave. W as 16 B-fragments in VGPRs (no LDS, no barriers).
// C/D: col = lane&15, row = (lane>>4)*4 + reg  [HW-verified layout].
__global__ __launch_bounds__(256) void k_gemm1(const float* __restrict__ x,
                                               const float* __restrict__ W,
                                               const float* __restrict__ dinv,
                                               __half* __restrict__ h1h, int N) {
  const int wid = threadIdx.x >> 6;
  const int lane = threadIdx.x & 63;
  const int n = lane & 15;
  const int g = lane >> 4;

  const int ntiles = (N + 15) >> 4;
  const int tile = blockIdx.x * 4 + wid;
  if (tile >= ntiles) return;

  f16x8 bf[16];
#pragma unroll
  for (int f = 0; f < 16; ++f) {
    const float* wp = W + (size_t)(f * 32 + g * 8) * HID + n;
#pragma unroll
    for (int j = 0; j < 8; ++j) bf[f][j] = (_Float16)wp[j * HID];
  }

  int rowbase = tile * 16;
  if (rowbase + 16 > N) rowbase = N - 16;  // overlap-safe: rewrites same values
  const float* xr = x + (size_t)(rowbase + n) * NFEAT + g * 8;

  f32x4 acc = {0.f, 0.f, 0.f, 0.f};
#pragma unroll
  for (int f = 0; f < 16; ++f) {
    float4 p0 = *(const float4*)(xr + f * 32);
    float4 p1 = *(const float4*)(xr + f * 32 + 4);
    f16x8 af;
    af[0] = (_Float16)p0.x; af[1] = (_Float16)p0.y;
    af[2] = (_Float16)p0.z; af[3] = (_Float16)p0.w;
    af[4] = (_Float16)p1.x; af[5] = (_Float16)p1.y;
    af[6] = (_Float16)p1.z; af[7] = (_Float16)p1.w;
    acc = __builtin_amdgcn_mfma_f32_16x16x32_f16(af, bf[f], acc, 0, 0, 0);
  }

#pragma unroll
  for (int r = 0; r < 4; ++r) {
    int row = rowbase + g * 4 + r;
    h1h[(size_t)row * HID + n] = __float2half(acc[r] * dinv[row]);
  }
}

// ===== layer1 aggregation + relu + W2, fused. 16 lanes per node, fp16 h1. =====
__global__ __launch_bounds__(256) void k_agg1f(const int* __restrict__ rowbeg,
                                               const int* __restrict__ rowend,
                                               const int* __restrict__ csr,
                                               const __half* __restrict__ h1h,
                                               const float* __restrict__ dinv,
                                               const float* __restrict__ b1,
                                               const float* __restrict__ W2,
                                               float* __restrict__ h2s, int N) {
  const int f = threadIdx.x & 15;
  const int node = blockIdx.x * 16 + (threadIdx.x >> 4);
  if (node >= N) return;
  int j = rowbeg[node];
  const int end = rowend[node];
  float acc = __half2float(h1h[(size_t)node * HID + f]);  // self loop (pre-scaled)
  for (; j < end && (j & 3); ++j) acc += __half2float(h1h[(size_t)csr[j] * HID + f]);
  for (; j + 8 <= end; j += 8) {
    int4 s0 = *(const int4*)&csr[j];
    int4 s1 = *(const int4*)&csr[j + 4];
    float a0 = __half2float(h1h[(size_t)s0.x * HID + f]);
    float a1 = __half2float(h1h[(size_t)s0.y * HID + f]);
    float a2 = __half2float(h1h[(size_t)s0.z * HID + f]);
    float a3 = __half2float(h1h[(size_t)s0.w * HID + f]);
    float a4 = __half2float(h1h[(size_t)s1.x * HID + f]);
    float a5 = __half2float(h1h[(size_t)s1.y * HID + f]);
    float a6 = __half2float(h1h[(size_t)s1.z * HID + f]);
    float a7 = __half2float(h1h[(size_t)s1.w * HID + f]);
    acc += ((a0 + a1) + (a2 + a3)) + ((a4 + a5) + (a6 + a7));
  }
  for (; j + 4 <= end; j += 4) {
    int4 ss = *(const int4*)&csr[j];
    float a0 = __half2float(h1h[(size_t)ss.x * HID + f]);
    float a1 = __half2float(h1h[(size_t)ss.y * HID + f]);
    float a2 = __half2float(h1h[(size_t)ss.z * HID + f]);
    float a3 = __half2float(h1h[(size_t)ss.w * HID + f]);
    acc += (a0 + a1) + (a2 + a3);
  }
  for (; j < end; ++j) acc += __half2float(h1h[(size_t)csr[j] * HID + f]);

  float di = dinv[node];
  float v = fmaxf(acc * di + b1[f], 0.f);
  float o0 = v * W2[f * 2 + 0];
  float o1 = v * W2[f * 2 + 1];
#pragma unroll
  for (int d = 1; d < 16; d <<= 1) {
    o0 += __shfl_xor(o0, d);
    o1 += __shfl_xor(o1, d);
  }
  if (f == 0) *(float2*)&h2s[(size_t)node * 2] = make_float2(o0 * di, o1 * di);
}

// ===== layer2 aggregation + bias, fused. thread per node. =====
__global__ __launch_bounds__(256) void k_agg2f(const int* __restrict__ rowbeg,
                                               const int* __restrict__ rowend,
                                               const int* __restrict__ csr,
                                               const float* __restrict__ h2s,
                                               const float* __restrict__ dinv,
                                               const float* __restrict__ b2,
                                               float* __restrict__ out, int N) {
  int i = blockIdx.x * 256 + threadIdx.x;
  if (i >= N) return;
  int j = rowbeg[i];
  const int end = rowend[i];
  float2 o = *(const float2*)&h2s[(size_t)i * 2];  // self loop
  for (; j < end && (j & 3); ++j) {
    float2 v = *(const float2*)&h2s[(size_t)csr[j] * 2];
    o.x += v.x; o.y += v.y;
  }
  for (; j + 4 <= end; j += 4) {
    int4 ss = *(const int4*)&csr[j];
    float2 v0 = *(const float2*)&h2s[(size_t)ss.x * 2];
    float2 v1 = *(const float2*)&h2s[(size_t)ss.y * 2];
    float2 v2 = *(const float2*)&h2s[(size_t)ss.z * 2];
    float2 v3 = *(const float2*)&h2s[(size_t)ss.w * 2];
    o.x += (v0.x + v1.x) + (v2.x + v3.x);
    o.y += (v0.y + v1.y) + (v2.y + v3.y);
  }
  for (; j < end; ++j) {
    float2 v = *(const float2*)&h2s[(size_t)csr[j] * 2];
    o.x += v.x; o.y += v.y;
  }
  float di = dinv[i];
  o.x = o.x * di + b2[0];
  o.y = o.y * di + b2[1];
  *(float2*)&out[(size_t)i * 2] = o;
}

// ================= launch =================
extern "C" void kernel_launch(void* const* d_in, const int* in_sizes, int n_in,
                              void* d_out, int out_size, void* d_ws, size_t ws_size,
                              hipStream_t stream) {
  const float* x = (const float*)d_in[0];
  const int* ei = (const int*)d_in[1];  // harness delivers integer inputs as int32
  const float* W1 = (const float*)d_in[2];
  const float* b1 = (const float*)d_in[3];
  const float* W2 = (const float*)d_in[4];
  const float* b2 = (const float*)d_in[5];
  float* out = (float*)d_out;
  const int N = in_sizes[0] / NFEAT;
  const int E = in_sizes[1] / 2;
  const int nb = (N + 255) / 256;  // buckets of 256 nodes

  char* p = (char*)d_ws;
  int* cnt_t = (int*)p;    p += (size_t)MAXNB * NBLK * 4;
  int* off_t = (int*)p;    p += (size_t)MAXNB * NBLK * 4;
  int* gcnt = (int*)p;     p += (size_t)MAXNB * 4;
  int* gbase = (int*)p;    p += (size_t)MAXNB * 4;
  int* binned = (int*)p;   p += ((size_t)E + MAXNB * 16) * 4;
  int* csr = (int*)p;      p += ((size_t)E + MAXNB * 16) * 4;
  int* rowbeg = (int*)p;   p += (size_t)N * 4;
  int* rowend = (int*)p;   p += (size_t)N * 4;
  float* dinv = (float*)p; p += (size_t)N * 4;
  __half* h1h = (__half*)p; p += (size_t)N * HID * 2;
  float* h2s = (float*)p;  p += (size_t)N * 2 * 4;

  const int ntiles = (N + 15) / 16;
  const int gblocks = (ntiles + 3) / 4;  // one tile per wave

  k_hist2d<<<NBLK, 512, 0, stream>>>(ei, cnt_t, E, nb);
  k_colscan<<<nb, 64, 0, stream>>>(cnt_t, off_t, gcnt, nb);
  k_bscan<<<1, 512, 0, stream>>>(gcnt, gbase, nb);
  k_scatter2<<<NBLK, 512, 0, stream>>>(ei, gbase, off_t, binned, E, nb);
  k_sortbucket<<<nb, 512, 0, stream>>>(gbase, gcnt, binned, csr, rowbeg, rowend, dinv, N);
  k_gemm1<<<gblocks, 256, 0, stream>>>(x, W1, dinv, h1h, N);
  k_agg1f<<<(N + 15) / 16, 256, 0, stream>>>(rowbeg, rowend, csr, h1h, dinv, b1, W2, h2s, N);
  k_agg2f<<<(N + 255) / 256, 256, 0, stream>>>(rowbeg, rowend, csr, h2s, dinv, b2, out, N);
}

// Round 16
// 166.254 us; speedup vs baseline: 1.4100x; 1.0071x over previous
//
#include <hip/hip_runtime.h>
#include <hip/hip_fp16.h>

#define NFEAT 512
#define HID 16
#define MAXNB 512          // max buckets (N/256 = 391 for N=100K)
#define NBLK 512           // hist/scatter blocks within merged kernels
#define PACK_SHIFT 17      // src fits in 17 bits (N < 131072)
#define PACK_MASK ((1 << PACK_SHIFT) - 1)

typedef _Float16 f16x8 __attribute__((ext_vector_type(8)));
typedef float f32x4 __attribute__((ext_vector_type(4)));

// ---- shared device helper: one 16x16 MFMA tile of x@W1 (unscaled, fp16 out) ----
__device__ __forceinline__ void gemm_tile(const float* __restrict__ x,
                                          const float* __restrict__ W,
                                          __half* __restrict__ h1u,
                                          int tile, int N, int lane) {
  const int n = lane & 15;
  const int g = lane >> 4;

  f16x8 bf[16];
#pragma unroll
  for (int f = 0; f < 16; ++f) {
    const float* wp = W + (size_t)(f * 32 + g * 8) * HID + n;
#pragma unroll
    for (int j = 0; j < 8; ++j) bf[f][j] = (_Float16)wp[j * HID];
  }

  int rowbase = tile * 16;
  if (rowbase + 16 > N) rowbase = N - 16;  // overlap-safe: rewrites same values
  const float* xr = x + (size_t)(rowbase + n) * NFEAT + g * 8;

  f32x4 acc = {0.f, 0.f, 0.f, 0.f};
#pragma unroll
  for (int f = 0; f < 16; ++f) {
    float4 p0 = *(const float4*)(xr + f * 32);
    float4 p1 = *(const float4*)(xr + f * 32 + 4);
    f16x8 af;
    af[0] = (_Float16)p0.x; af[1] = (_Float16)p0.y;
    af[2] = (_Float16)p0.z; af[3] = (_Float16)p0.w;
    af[4] = (_Float16)p1.x; af[5] = (_Float16)p1.y;
    af[6] = (_Float16)p1.z; af[7] = (_Float16)p1.w;
    acc = __builtin_amdgcn_mfma_f32_16x16x32_f16(af, bf[f], acc, 0, 0, 0);
  }

#pragma unroll
  for (int r = 0; r < 4; ++r) {
    int row = rowbase + g * 4 + r;
    h1u[(size_t)row * HID + n] = __float2half(acc[r]);
  }
}

// ============ K1: hist2d (blocks < NBLK)  ||  gemm tiles [0, tsplit) ============
__global__ __launch_bounds__(512) void k_hist_gemm(const int* __restrict__ ei,
                                                   int* __restrict__ cnt_t,
                                                   int E, int nb,
                                                   const float* __restrict__ x,
                                                   const float* __restrict__ W,
                                                   __half* __restrict__ h1u,
                                                   int N, int tsplit) {
  __shared__ int l[MAXNB];
  if (blockIdx.x < NBLK) {
    for (int i = threadIdx.x; i < nb; i += 512) l[i] = 0;
    __syncthreads();
    int chunk = (E + NBLK - 1) / NBLK;
    int beg = blockIdx.x * chunk;
    int end = beg + chunk; if (end > E) end = E;
    for (int e = beg + threadIdx.x; e < end; e += 512)
      atomicAdd(&l[ei[(size_t)E + e] >> 8], 1);
    __syncthreads();
    for (int b = threadIdx.x; b < nb; b += 512)
      cnt_t[(size_t)b * NBLK + blockIdx.x] = l[b];
  } else {
    int tile = (blockIdx.x - NBLK) * 8 + (threadIdx.x >> 6);
    if (tile < tsplit) gemm_tile(x, W, h1u, tile, N, threadIdx.x & 63);
  }
}

// ============ per-bucket column scan (one wave per bucket, 8 counts/lane) ====
__global__ __launch_bounds__(64) void k_colscan(const int* __restrict__ cnt_t,
                                                int* __restrict__ off_t,
                                                int* __restrict__ gcnt, int nb) {
  int b = blockIdx.x;
  if (b >= nb) return;
  int lane = threadIdx.x;
  int4 v0 = *(const int4*)&cnt_t[(size_t)b * NBLK + lane * 8];
  int4 v1 = *(const int4*)&cnt_t[(size_t)b * NBLK + lane * 8 + 4];
  int tot = (v0.x + v0.y + v0.z + v0.w) + (v1.x + v1.y + v1.z + v1.w);
  int s = tot;
  for (int d = 1; d < 64; d <<= 1) {
    int o = __shfl_up(s, d);
    if (lane >= d) s += o;
  }
  int excl = s - tot;
  int4 w0, w1;
  w0.x = excl;
  w0.y = w0.x + v0.x;
  w0.z = w0.y + v0.y;
  w0.w = w0.z + v0.z;
  w1.x = w0.w + v0.w;
  w1.y = w1.x + v1.x;
  w1.z = w1.y + v1.y;
  w1.w = w1.z + v1.z;
  *(int4*)&off_t[(size_t)b * NBLK + lane * 8] = w0;
  *(int4*)&off_t[(size_t)b * NBLK + lane * 8 + 4] = w1;
  if (lane == 63) gcnt[b] = s;
}

// ============ scan: 16-aligned bucket bases ============
__global__ __launch_bounds__(512) void k_bscan(const int* __restrict__ gcnt,
                                               int* __restrict__ gbase, int nb) {
  __shared__ int sm[512];
  int t = threadIdx.x;
  int c = (t < nb) ? gcnt[t] : 0;
  int pc = (c + 15) & ~15;
  sm[t] = pc;
  __syncthreads();
  for (int off = 1; off < 512; off <<= 1) {
    int x = (t >= off) ? sm[t - off] : 0;
    __syncthreads();
    sm[t] += x;
    __syncthreads();
  }
  if (t < nb) gbase[t] = sm[t] - pc;
}

// ============ K3: scatter (blocks < NBLK)  ||  gemm tiles [tsplit, ntiles) ======
__global__ __launch_bounds__(512) void k_scatter_gemm(const int* __restrict__ ei,
                                                      const int* __restrict__ gbase,
                                                      const int* __restrict__ off_t,
                                                      int* __restrict__ binned,
                                                      int E, int nb,
                                                      const float* __restrict__ x,
                                                      const float* __restrict__ W,
                                                      __half* __restrict__ h1u,
                                                      int N, int tsplit, int ntiles) {
  __shared__ int cur[MAXNB];
  if (blockIdx.x < NBLK) {
    for (int b = threadIdx.x; b < nb; b += 512)
      cur[b] = gbase[b] + off_t[(size_t)b * NBLK + blockIdx.x];
    __syncthreads();
    int chunk = (E + NBLK - 1) / NBLK;
    int beg = blockIdx.x * chunk;
    int end = beg + chunk; if (end > E) end = E;
    for (int e = beg + threadIdx.x; e < end; e += 512) {
      int s = ei[e];
      int d = ei[(size_t)E + e];
      int b = d >> 8;
      int pos = atomicAdd(&cur[b], 1);
      binned[pos] = s | ((d & 255) << PACK_SHIFT);
    }
  } else {
    int tile = tsplit + (blockIdx.x - NBLK) * 8 + (threadIdx.x >> 6);
    if (tile < ntiles) gemm_tile(x, W, h1u, tile, N, threadIdx.x & 63);
  }
}

// ====== per-bucket sort -> per-node CSR + dinv + h1 rescale (512 thr) ======
__global__ __launch_bounds__(512) void k_sortbucket(const int* __restrict__ gbase,
                                                    const int* __restrict__ gcnt,
                                                    const int* __restrict__ binned,
                                                    int* __restrict__ csr,
                                                    int* __restrict__ rowbeg,
                                                    int* __restrict__ rowend,
                                                    float* __restrict__ dinv,
                                                    __half* __restrict__ h1h, int N) {
  __shared__ int hist[256];
  __shared__ int sm[256];
  __shared__ int cur[256];
  __shared__ float sdinv[256];
  const int t = threadIdx.x;
  const int b = blockIdx.x;
  const int base = gbase[b], cnt = gcnt[b];
  if (t < 256) hist[t] = 0;
  __syncthreads();
  for (int j = base + t; j < base + cnt; j += 512)
    atomicAdd(&hist[binned[j] >> PACK_SHIFT], 1);
  __syncthreads();
  int h = 0;
  if (t < 256) {
    h = hist[t];
    sm[t] = h;
  }
  __syncthreads();
  for (int off = 1; off < 256; off <<= 1) {
    int x = 0;
    if (t < 256 && t >= off) x = sm[t - off];
    __syncthreads();
    if (t < 256) sm[t] += x;
    __syncthreads();
  }
  if (t < 256) {
    int incl = sm[t];
    int excl = incl - h;
    cur[t] = excl;
    float dv = rsqrtf((float)h + 1.0f);
    sdinv[t] = dv;
    int node = b * 256 + t;
    if (node < N) {
      rowbeg[node] = base + excl;
      rowend[node] = base + incl;
      dinv[node] = dv;
    }
  }
  __syncthreads();
  for (int j = base + t; j < base + cnt; j += 512) {
    int val = binned[j];
    int pos = atomicAdd(&cur[val >> PACK_SHIFT], 1);
    csr[base + pos] = val & PACK_MASK;
  }
  // rescale h1u -> h1h in place: thread t handles half a row (8 fp16)
  {
    int node = b * 256 + (t >> 1);
    if (node < N) {
      float dv = sdinv[t >> 1];
      __half* hp = h1h + (size_t)node * HID + (t & 1) * 8;
      f16x8 v = *(const f16x8*)hp;
#pragma unroll
      for (int j = 0; j < 8; ++j) v[j] = (_Float16)((float)v[j] * dv);
      *(f16x8*)hp = v;
    }
  }
}

// ===== layer1 aggregation + relu + W2, fused. 16 lanes per node, fp16 h1. =====
__global__ __launch_bounds__(256) void k_agg1f(const int* __restrict__ rowbeg,
                                               const int* __restrict__ rowend,
                                               const int* __restrict__ csr,
                                               const __half* __restrict__ h1h,
                                               const float* __restrict__ dinv,
                                               const float* __restrict__ b1,
                                               const float* __restrict__ W2,
                                               float* __restrict__ h2s, int N) {
  const int f = threadIdx.x & 15;
  const int node = blockIdx.x * 16 + (threadIdx.x >> 4);
  if (node >= N) return;
  int j = rowbeg[node];
  const int end = rowend[node];
  float acc = __half2float(h1h[(size_t)node * HID + f]);  // self loop (pre-scaled)
  for (; j < end && (j & 3); ++j) acc += __half2float(h1h[(size_t)csr[j] * HID + f]);
  for (; j + 8 <= end; j += 8) {
    int4 s0 = *(const int4*)&csr[j];
    int4 s1 = *(const int4*)&csr[j + 4];
    float a0 = __half2float(h1h[(size_t)s0.x * HID + f]);
    float a1 = __half2float(h1h[(size_t)s0.y * HID + f]);
    float a2 = __half2float(h1h[(size_t)s0.z * HID + f]);
    float a3 = __half2float(h1h[(size_t)s0.w * HID + f]);
    float a4 = __half2float(h1h[(size_t)s1.x * HID + f]);
    float a5 = __half2float(h1h[(size_t)s1.y * HID + f]);
    float a6 = __half2float(h1h[(size_t)s1.z * HID + f]);
    float a7 = __half2float(h1h[(size_t)s1.w * HID + f]);
    acc += ((a0 + a1) + (a2 + a3)) + ((a4 + a5) + (a6 + a7));
  }
  for (; j + 4 <= end; j += 4) {
    int4 ss = *(const int4*)&csr[j];
    float a0 = __half2float(h1h[(size_t)ss.x * HID + f]);
    float a1 = __half2float(h1h[(size_t)ss.y * HID + f]);
    float a2 = __half2float(h1h[(size_t)ss.z * HID + f]);
    float a3 = __half2float(h1h[(size_t)ss.w * HID + f]);
    acc += (a0 + a1) + (a2 + a3);
  }
  for (; j < end; ++j) acc += __half2float(h1h[(size_t)csr[j] * HID + f]);

  float di = dinv[node];
  float v = fmaxf(acc * di + b1[f], 0.f);
  float o0 = v * W2[f * 2 + 0];
  float o1 = v * W2[f * 2 + 1];
#pragma unroll
  for (int d = 1; d < 16; d <<= 1) {
    o0 += __shfl_xor(o0, d);
    o1 += __shfl_xor(o1, d);
  }
  if (f == 0) *(float2*)&h2s[(size_t)node * 2] = make_float2(o0 * di, o1 * di);
}

// ===== layer2 aggregation + bias, fused. thread per node. =====
__global__ __launch_bounds__(256) void k_agg2f(const int* __restrict__ rowbeg,
                                               const int* __restrict__ rowend,
                                               const int* __restrict__ csr,
                                               const float* __restrict__ h2s,
                                               const float* __restrict__ dinv,
                                               const float* __restrict__ b2,
                                               float* __restrict__ out, int N) {
  int i = blockIdx.x * 256 + threadIdx.x;
  if (i >= N) return;
  int j = rowbeg[i];
  const int end = rowend[i];
  float2 o = *(const float2*)&h2s[(size_t)i * 2];  // self loop
  for (; j < end && (j & 3); ++j) {
    float2 v = *(const float2*)&h2s[(size_t)csr[j] * 2];
    o.x += v.x; o.y += v.y;
  }
  for (; j + 8 <= end; j += 8) {
    int4 s0 = *(const int4*)&csr[j];
    int4 s1 = *(const int4*)&csr[j + 4];
    float2 v0 = *(const float2*)&h2s[(size_t)s0.x * 2];
    float2 v1 = *(const float2*)&h2s[(size_t)s0.y * 2];
    float2 v2 = *(const float2*)&h2s[(size_t)s0.z * 2];
    float2 v3 = *(const float2*)&h2s[(size_t)s0.w * 2];
    float2 v4 = *(const float2*)&h2s[(size_t)s1.x * 2];
    float2 v5 = *(const float2*)&h2s[(size_t)s1.y * 2];
    float2 v6 = *(const float2*)&h2s[(size_t)s1.z * 2];
    float2 v7 = *(const float2*)&h2s[(size_t)s1.w * 2];
    o.x += ((v0.x + v1.x) + (v2.x + v3.x)) + ((v4.x + v5.x) + (v6.x + v7.x));
    o.y += ((v0.y + v1.y) + (v2.y + v3.y)) + ((v4.y + v5.y) + (v6.y + v7.y));
  }
  for (; j + 4 <= end; j += 4) {
    int4 ss = *(const int4*)&csr[j];
    float2 v0 = *(const float2*)&h2s[(size_t)ss.x * 2];
    float2 v1 = *(const float2*)&h2s[(size_t)ss.y * 2];
    float2 v2 = *(const float2*)&h2s[(size_t)ss.z * 2];
    float2 v3 = *(const float2*)&h2s[(size_t)ss.w * 2];
    o.x += (v0.x + v1.x) + (v2.x + v3.x);
    o.y += (v0.y + v1.y) + (v2.y + v3.y);
  }
  for (; j < end; ++j) {
    float2 v = *(const float2*)&h2s[(size_t)csr[j] * 2];
    o.x += v.x; o.y += v.y;
  }
  float di = dinv[i];
  o.x = o.x * di + b2[0];
  o.y = o.y * di + b2[1];
  *(float2*)&out[(size_t)i * 2] = o;
}

// ================= launch =================
extern "C" void kernel_launch(void* const* d_in, const int* in_sizes, int n_in,
                              void* d_out, int out_size, void* d_ws, size_t ws_size,
                              hipStream_t stream) {
  const float* x = (const float*)d_in[0];
  const int* ei = (const int*)d_in[1];  // harness delivers integer inputs as int32
  const float* W1 = (const float*)d_in[2];
  const float* b1 = (const float*)d_in[3];
  const float* W2 = (const float*)d_in[4];
  const float* b2 = (const float*)d_in[5];
  float* out = (float*)d_out;
  const int N = in_sizes[0] / NFEAT;
  const int E = in_sizes[1] / 2;
  const int nb = (N + 255) / 256;  // buckets of 256 nodes

  char* p = (char*)d_ws;
  int* cnt_t = (int*)p;    p += (size_t)MAXNB * NBLK * 4;
  int* off_t = (int*)p;    p += (size_t)MAXNB * NBLK * 4;
  int* gcnt = (int*)p;     p += (size_t)MAXNB * 4;
  int* gbase = (int*)p;    p += (size_t)MAXNB * 4;
  int* binned = (int*)p;   p += ((size_t)E + MAXNB * 16) * 4;
  int* csr = (int*)p;      p += ((size_t)E + MAXNB * 16) * 4;
  int* rowbeg = (int*)p;   p += (size_t)N * 4;
  int* rowend = (int*)p;   p += (size_t)N * 4;
  float* dinv = (float*)p; p += (size_t)N * 4;
  __half* h1h = (__half*)p; p += (size_t)N * HID * 2;
  float* h2s = (float*)p;  p += (size_t)N * 2 * 4;

  const int ntiles = (N + 15) / 16;
  const int tsplit = ((ntiles / 2) + 7) & ~7;           // first-half tiles, x8 aligned
  const int gA = (tsplit + 7) / 8;                       // gemm blocks in K1
  const int gB = (ntiles - tsplit + 7) / 8;              // gemm blocks in K3

  k_hist_gemm<<<NBLK + gA, 512, 0, stream>>>(ei, cnt_t, E, nb, x, W1, h1h, N, tsplit);
  k_colscan<<<nb, 64, 0, stream>>>(cnt_t, off_t, gcnt, nb);
  k_bscan<<<1, 512, 0, stream>>>(gcnt, gbase, nb);
  k_scatter_gemm<<<NBLK + gB, 512, 0, stream>>>(ei, gbase, off_t, binned, E, nb,
                                                x, W1, h1h, N, tsplit, ntiles);
  k_sortbucket<<<nb, 512, 0, stream>>>(gbase, gcnt, binned, csr, rowbeg, rowend,
                                       dinv, h1h, N);
  k_agg1f<<<(N + 15) / 16, 256, 0, stream>>>(rowbeg, rowend, csr, h1h, dinv, b1, W2, h2s, N);
  k_agg2f<<<(N + 255) / 256, 256, 0, stream>>>(rowbeg, rowend, csr, h2s, dinv, b2, out, N);
}